// Round 14
// baseline (833.955 us; speedup 1.0000x reference)
//
#include <hip/hip_runtime.h>
#include <hip/hip_bf16.h>

#define B_ 2
#define S_ 2048
#define E_ 2048
#define H_ 16
#define D_ 128
#define I_ 8192
#define T_ (B_*S_)

typedef __attribute__((ext_vector_type(8))) short bf16x8;      // 8 bf16 in 4 VGPRs
typedef __attribute__((ext_vector_type(8))) unsigned short us8;
typedef __attribute__((ext_vector_type(4))) float f32x4;
typedef __attribute__((ext_vector_type(16))) float f32x16;

__device__ __forceinline__ unsigned short f2bf(float f) {
  union { float f; unsigned int u; } c; c.f = f;
  unsigned int u = c.u;
  unsigned int r = (u + 0x7fffu + ((u >> 16) & 1u)) >> 16;
  return (unsigned short)r;
}

__device__ __forceinline__ void gload16(const void* g, void* l) {
  __builtin_amdgcn_global_load_lds((const __attribute__((address_space(1))) void*)g,
                                   (__attribute__((address_space(3))) void*)l, 16, 0, 0);
}

// ---------------- weight fp32 (K,N) -> bf16 (N,K) transpose ----------------
__global__ void transpose_w(const float* __restrict__ in, unsigned short* __restrict__ out,
                            int K, int N) {
  __shared__ float tile[32][33];
  const int n0 = blockIdx.x * 32, k0 = blockIdx.y * 32;
  const int tx = threadIdx.x, ty = threadIdx.y;
#pragma unroll
  for (int j = 0; j < 4; ++j) {
    int k = k0 + ty + j * 8;
    tile[ty + j * 8][tx] = in[(size_t)k * N + n0 + tx];
  }
  __syncthreads();
#pragma unroll
  for (int j = 0; j < 4; ++j) {
    int n = n0 + ty + j * 8;
    out[(size_t)n * K + k0 + tx] = f2bf(tile[tx][ty + j * 8]);
  }
}

// ---------------- LayerNorm: fp32 (T,E) -> bf16 (T,E) ----------------
__global__ void ln_kernel(const float* __restrict__ x, const float* __restrict__ w,
                          const float* __restrict__ b, unsigned short* __restrict__ out) {
  const int row = blockIdx.x;
  const int tid = threadIdx.x;
  const int wid = tid >> 6, lane = tid & 63;
  const float4* xr = (const float4*)(x + (size_t)row * E_);
  float4 v0 = xr[tid * 2], v1 = xr[tid * 2 + 1];
  float s  = v0.x + v0.y + v0.z + v0.w + v1.x + v1.y + v1.z + v1.w;
  float sq = v0.x*v0.x + v0.y*v0.y + v0.z*v0.z + v0.w*v0.w
           + v1.x*v1.x + v1.y*v1.y + v1.z*v1.z + v1.w*v1.w;
#pragma unroll
  for (int off = 32; off > 0; off >>= 1) {
    s  += __shfl_xor(s, off);
    sq += __shfl_xor(sq, off);
  }
  __shared__ float red[8];
  if (lane == 0) { red[wid] = s; red[wid + 4] = sq; }
  __syncthreads();
  s  = red[0] + red[1] + red[2] + red[3];
  sq = red[4] + red[5] + red[6] + red[7];
  const float mu  = s * (1.0f / E_);
  const float var = sq * (1.0f / E_) - mu * mu;
  const float rstd = rsqrtf(var + 1e-5f);
  const float4* w4 = (const float4*)w + tid * 2;
  const float4* b4 = (const float4*)b + tid * 2;
  float4 w0 = w4[0], w1 = w4[1], bb0 = b4[0], bb1 = b4[1];
  us8 o;
  o[0] = f2bf((v0.x - mu) * rstd * w0.x + bb0.x);
  o[1] = f2bf((v0.y - mu) * rstd * w0.y + bb0.y);
  o[2] = f2bf((v0.z - mu) * rstd * w0.z + bb0.z);
  o[3] = f2bf((v0.w - mu) * rstd * w0.w + bb0.w);
  o[4] = f2bf((v1.x - mu) * rstd * w1.x + bb1.x);
  o[5] = f2bf((v1.y - mu) * rstd * w1.y + bb1.y);
  o[6] = f2bf((v1.z - mu) * rstd * w1.z + bb1.z);
  o[7] = f2bf((v1.w - mu) * rstd * w1.w + bb1.w);
  *(us8*)(&out[(size_t)row * E_ + tid * 8]) = o;
}

// ---------------- 128x128 GEMM, 32x32x16 MFMA, BK=64 (R9 layout) ----------------
template<int EPI>
__global__ __launch_bounds__(256, 3)
void gemm32(const unsigned short* __restrict__ A,
            const unsigned short* __restrict__ Bt,
            void* __restrict__ Cout,
            const float* __restrict__ resid,
            int M, int N, int K) {
  __shared__ __align__(16) unsigned short As[128 * 64];
  __shared__ __align__(16) unsigned short Bs[128 * 64];
  const int gn = N >> 7;
  const int nwg = (M >> 7) * gn;
  const int cpx = nwg >> 3;
  const int bid = blockIdx.x;
  const int swz = (bid & 7) * cpx + (bid >> 3);
  const int bm = swz / gn, bn = swz % gn;
  const int tid = threadIdx.x;
  const int wid = tid >> 6, lane = tid & 63;
  const int wr = wid >> 1, wc = wid & 1;
  const int r31 = lane & 31, hi = lane >> 5;
  const int rsw = r31 & 7;

  const int trow = tid >> 3;                      // 0..31
  const int tc = (tid & 7) ^ (trow & 7);          // chunk 0..7
  const unsigned short* gA = A  + (size_t)(bm * 128 + trow) * K + tc * 8;
  const unsigned short* gB = Bt + (size_t)(bn * 128 + trow) * K + tc * 8;
  unsigned short* lA = &As[tid * 8];
  unsigned short* lB = &Bs[tid * 8];

  f32x16 acc[2][2] = {};
  const int nk = K >> 6;
  for (int kt = 0; kt < nk; ++kt) {
    __syncthreads();
#pragma unroll
    for (int s = 0; s < 4; ++s) {
      gload16(gA + (size_t)(s * 32) * K, lA + s * 2048);
      gload16(gB + (size_t)(s * 32) * K, lB + s * 2048);
    }
    gA += 64; gB += 64;
    __syncthreads();
#pragma unroll
    for (int ks = 0; ks < 4; ++ks) {
      const int ca = ((ks * 2 + hi) ^ rsw) * 8;   // swizzled chunk offset (shorts)
      bf16x8 a0 = *(const bf16x8*)(&As[(wr * 64 +      r31) * 64 + ca]);
      bf16x8 a1 = *(const bf16x8*)(&As[(wr * 64 + 32 + r31) * 64 + ca]);
      bf16x8 b0 = *(const bf16x8*)(&Bs[(wc * 64 +      r31) * 64 + ca]);
      bf16x8 b1 = *(const bf16x8*)(&Bs[(wc * 64 + 32 + r31) * 64 + ca]);
      acc[0][0] = __builtin_amdgcn_mfma_f32_32x32x16_bf16(a0, b0, acc[0][0], 0, 0, 0);
      acc[0][1] = __builtin_amdgcn_mfma_f32_32x32x16_bf16(a0, b1, acc[0][1], 0, 0, 0);
      acc[1][0] = __builtin_amdgcn_mfma_f32_32x32x16_bf16(a1, b0, acc[1][0], 0, 0, 0);
      acc[1][1] = __builtin_amdgcn_mfma_f32_32x32x16_bf16(a1, b1, acc[1][1], 0, 0, 0);
    }
  }

  const int row0 = bm * 128 + wr * 64;
  const int col0 = bn * 128 + wc * 64;
#pragma unroll
  for (int mt = 0; mt < 2; ++mt) {
#pragma unroll
    for (int nt = 0; nt < 2; ++nt) {
#pragma unroll
      for (int rg = 0; rg < 16; ++rg) {
        const int rl = (rg & 3) + 8 * (rg >> 2) + 4 * hi;
        const int row = row0 + mt * 32 + rl;
        const int col = col0 + nt * 32 + r31;
        const size_t idx = (size_t)row * N + col;
        const float v = acc[mt][nt][rg];
        if constexpr (EPI == 0) {
          ((unsigned short*)Cout)[idx] = f2bf(v);
        } else if constexpr (EPI == 1) {
          const float u = 0.7978845608028654f * (v + 0.044715f * v * v * v);
          const float gel = 0.5f * v * (1.0f + tanhf(u));
          ((unsigned short*)Cout)[idx] = f2bf(gel);
        } else {
          ((float*)Cout)[idx] = v + resid[idx];
        }
      }
    }
  }
}

// ---------------- 128x256 GEMM, 32x32x16 MFMA, BK=64, per-wave 64x128 ----------------
template<int EPI>
__global__ __launch_bounds__(256, 2)
void gemmW(const unsigned short* __restrict__ A,
           const unsigned short* __restrict__ Bt,
           void* __restrict__ Cout,
           const float* __restrict__ resid,
           int M, int N, int K) {
  __shared__ __align__(16) unsigned short As[128 * 64];   // 16 KB
  __shared__ __align__(16) unsigned short Bs[256 * 64];   // 32 KB
  const int gn = N >> 8;
  const int nwg = (M >> 7) * gn;
  const int cpx = nwg >> 3;                 // nwg % 8 == 0 for qkv(768)/W1(1024)
  const int bid = blockIdx.x;
  const int swz = (bid & 7) * cpx + (bid >> 3);
  const int bm = swz / gn, bn = swz % gn;
  const int tid = threadIdx.x;
  const int wid = tid >> 6, lane = tid & 63;
  const int wr = wid >> 1, wc = wid & 1;
  const int r31 = lane & 31, hi = lane >> 5;
  const int rsw = r31 & 7;

  const int trow = tid >> 3;                      // 0..31
  const int tc = (tid & 7) ^ (trow & 7);          // chunk 0..7
  const unsigned short* gA = A  + (size_t)(bm * 128 + trow) * K + tc * 8;
  const unsigned short* gB = Bt + (size_t)(bn * 256 + trow) * K + tc * 8;
  unsigned short* lA = &As[tid * 8];
  unsigned short* lB = &Bs[tid * 8];

  f32x16 acc[2][4] = {};
  const int nk = K >> 6;
  for (int kt = 0; kt < nk; ++kt) {
    __syncthreads();
#pragma unroll
    for (int s = 0; s < 4; ++s)
      gload16(gA + (size_t)(s * 32) * K, lA + s * 2048);
#pragma unroll
    for (int s = 0; s < 8; ++s)
      gload16(gB + (size_t)(s * 32) * K, lB + s * 2048);
    gA += 64; gB += 64;
    __syncthreads();
#pragma unroll
    for (int ks = 0; ks < 4; ++ks) {
      const int ca = ((ks * 2 + hi) ^ rsw) * 8;   // swizzled chunk offset (shorts)
      bf16x8 a0 = *(const bf16x8*)(&As[(wr * 64 +      r31) * 64 + ca]);
      bf16x8 a1 = *(const bf16x8*)(&As[(wr * 64 + 32 + r31) * 64 + ca]);
      bf16x8 bq[4];
#pragma unroll
      for (int nt = 0; nt < 4; ++nt)
        bq[nt] = *(const bf16x8*)(&Bs[(wc * 128 + nt * 32 + r31) * 64 + ca]);
#pragma unroll
      for (int nt = 0; nt < 4; ++nt) {
        acc[0][nt] = __builtin_amdgcn_mfma_f32_32x32x16_bf16(a0, bq[nt], acc[0][nt], 0, 0, 0);
        acc[1][nt] = __builtin_amdgcn_mfma_f32_32x32x16_bf16(a1, bq[nt], acc[1][nt], 0, 0, 0);
      }
    }
  }

  const int row0 = bm * 128 + wr * 64;
  const int col0 = bn * 256 + wc * 128;
#pragma unroll
  for (int mt = 0; mt < 2; ++mt) {
#pragma unroll
    for (int nt = 0; nt < 4; ++nt) {
#pragma unroll
      for (int rg = 0; rg < 16; ++rg) {
        const int rl = (rg & 3) + 8 * (rg >> 2) + 4 * hi;
        const int row = row0 + mt * 32 + rl;
        const int col = col0 + nt * 32 + r31;
        const size_t idx = (size_t)row * N + col;
        const float v = acc[mt][nt][rg];
        if constexpr (EPI == 0) {
          ((unsigned short*)Cout)[idx] = f2bf(v);
        } else if constexpr (EPI == 1) {
          const float u = 0.7978845608028654f * (v + 0.044715f * v * v * v);
          const float gel = 0.5f * v * (1.0f + tanhf(u));
          ((unsigned short*)Cout)[idx] = f2bf(gel);
        } else {
          ((float*)Cout)[idx] = v + resid[idx];
        }
      }
    }
  }
}

// ---------------- extract V^T: qkv (T,6144) -> vT (B,H,D,S) bf16 ----------------
__global__ void extract_vT(const unsigned short* __restrict__ qkv, unsigned short* __restrict__ vT) {
  __shared__ unsigned short tile[32][34];
  const int bh = blockIdx.z;               // b*H + h
  const int b = bh >> 4, h = bh & 15;
  const int s0 = blockIdx.y * 32, d0 = blockIdx.x * 32;
  const int tx = threadIdx.x, ty = threadIdx.y;
#pragma unroll
  for (int j = 0; j < 4; ++j) {
    int s = s0 + ty + j * 8;
    tile[ty + j * 8][tx] = qkv[(size_t)(b * S_ + s) * 6144 + 4096 + h * 128 + d0 + tx];
  }
  __syncthreads();
#pragma unroll
  for (int j = 0; j < 4; ++j) {
    int d = d0 + ty + j * 8;
    vT[((size_t)bh * 128 + d) * 2048 + s0 + tx] = tile[tx][ty + j * 8];
  }
}

// ---------------- causal flash attention, KVBLK=64, balanced pairing ----------------
// R13 null: KVBLK=128 halved fixed costs AND occupancy (LDS 37->69KB, 3->2
// blocks/CU) - exact cancel => attn is latency-chain-bound, TLP hides it.
// This round: restore KVBLK=64 (37KB -> 3 blocks/CU at (256,3); live regs
// ~139 <= 170 budget, no spill) + T13 defer-max (skip corr/rescale when
// tile max <= m0+8, wave-uniform __all; P bounded by e^8, fp32-safe).
__global__ __launch_bounds__(256, 3)
void attn_kernel(const unsigned short* __restrict__ qkv,
                 const unsigned short* __restrict__ vT,
                 unsigned short* __restrict__ outp) {
  __shared__ __align__(16) unsigned short Ks[64 * 128];    // 16 KB, swizzled
  __shared__ __align__(16) unsigned short Vts[128 * 64];   // 16 KB, swizzled
  __shared__ __align__(16) unsigned short Ps[4 * 16 * 40]; // 5 KB, per-wave P tile
  const int bx = blockIdx.x;               // 0..15
  const int bh = blockIdx.y;
  const int b = bh >> 4, h = bh & 15;
  const int tid = threadIdx.x, wid = tid >> 6, lane = tid & 63;
  const int fr = lane & 15, g = lane >> 4;

  const unsigned short* kbase = qkv + (size_t)(b * S_) * 6144 + 2048 + h * 128;
  const unsigned short* vbase = vT + (size_t)bh * 128 * 2048;
  unsigned short* Pw = &Ps[wid * 640];
  const float scale = 0.08838834764831845f;

  us8 kreg[4], vreg[4];
#pragma unroll
  for (int j = 0; j < 4; ++j) {
    const int cc = tid + 256 * j;
    kreg[j] = *(const us8*)(kbase + (size_t)(cc >> 4) * 6144 + (cc & 15) * 8);
    vreg[j] = *(const us8*)(vbase + (size_t)(cc >> 3) * 2048 + (cc & 7) * 8);
  }

  for (int hf = 0; hf < 2; ++hf) {
    const int qt = hf ? (31 - bx) : bx;

    const unsigned short* qptr = qkv + (size_t)(b * S_ + qt * 64 + wid * 16 + fr) * 6144 + h * 128;
    bf16x8 qf[4];
#pragma unroll
    for (int dc = 0; dc < 4; ++dc) qf[dc] = *(const bf16x8*)(qptr + dc * 32 + g * 8);

    float m0[4], l0[4];
#pragma unroll
    for (int r = 0; r < 4; ++r) { m0[r] = -1e30f; l0[r] = 0.0f; }
    f32x4 acc[8] = {};

    for (int kt = 0; kt <= qt; ++kt) {
      __syncthreads();
#pragma unroll
      for (int j = 0; j < 4; ++j) {
        const int cc = tid + 256 * j;
        const int krow = cc >> 4, kcp = cc & 15;
        *(us8*)(&Ks[krow * 128 + ((kcp * 8) ^ ((krow & 7) << 3))]) = kreg[j];
        const int drow = cc >> 3, vcp = cc & 7;
        *(us8*)(&Vts[drow * 64 + ((vcp * 8) ^ ((drow & 7) << 3))]) = vreg[j];
      }
      const int nk = (kt < qt) ? (kt + 1) : (hf == 0 ? 0 : -1);
      if (nk >= 0) {
#pragma unroll
        for (int j = 0; j < 4; ++j) {
          const int cc = tid + 256 * j;
          kreg[j] = *(const us8*)(kbase + (size_t)(nk * 64 + (cc >> 4)) * 6144 + (cc & 15) * 8);
          vreg[j] = *(const us8*)(vbase + (size_t)(cc >> 3) * 2048 + nk * 64 + (cc & 7) * 8);
        }
      }
      __syncthreads();

      f32x4 sc[4] = {};
      __builtin_amdgcn_s_setprio(1);
#pragma unroll
      for (int dc = 0; dc < 4; ++dc) {
#pragma unroll
        for (int sub = 0; sub < 4; ++sub) {
          const int row = sub * 16 + fr;
          bf16x8 kf = *(const bf16x8*)(&Ks[row * 128 + ((dc * 32 + g * 8) ^ ((row & 7) << 3))]);
          sc[sub] = __builtin_amdgcn_mfma_f32_16x16x32_bf16(qf[dc], kf, sc[sub], 0, 0, 0);
        }
      }
      __builtin_amdgcn_s_setprio(0);

      float p[4][4];
      const bool diag = (kt == qt);
#pragma unroll
      for (int sub = 0; sub < 4; ++sub) {
#pragma unroll
        for (int r = 0; r < 4; ++r) {
          float v = sc[sub][r] * scale;
          if (diag && (sub * 16 + fr > wid * 16 + g * 4 + r)) v = -1e30f;
          p[sub][r] = v;
        }
      }

      // row maxes for this tile
      float mx4[4];
      int small = 1;
#pragma unroll
      for (int r = 0; r < 4; ++r) {
        float mx = fmaxf(fmaxf(p[0][r], p[1][r]), fmaxf(p[2][r], p[3][r]));
#pragma unroll
        for (int off = 1; off < 16; off <<= 1) mx = fmaxf(mx, __shfl_xor(mx, off));
        mx4[r] = mx;
        small &= (mx <= m0[r] + 8.0f) ? 1 : 0;
      }
      if (__all(small)) {
        // defer-max: keep old m0, no rescale (P bounded by e^8)
#pragma unroll
        for (int r = 0; r < 4; ++r) {
          float rs = 0.0f;
#pragma unroll
          for (int sub = 0; sub < 4; ++sub) { p[sub][r] = __expf(p[sub][r] - m0[r]); rs += p[sub][r]; }
#pragma unroll
          for (int off = 1; off < 16; off <<= 1) rs += __shfl_xor(rs, off);
          l0[r] += rs;
        }
      } else {
#pragma unroll
        for (int r = 0; r < 4; ++r) {
          const float mn = fmaxf(m0[r], mx4[r]);
          const float corr = __expf(m0[r] - mn);
          m0[r] = mn;
          float rs = 0.0f;
#pragma unroll
          for (int sub = 0; sub < 4; ++sub) { p[sub][r] = __expf(p[sub][r] - mn); rs += p[sub][r]; }
#pragma unroll
          for (int off = 1; off < 16; off <<= 1) rs += __shfl_xor(rs, off);
          l0[r] = l0[r] * corr + rs;
#pragma unroll
          for (int dt = 0; dt < 8; ++dt) acc[dt][r] *= corr;
        }
      }

#pragma unroll
      for (int half = 0; half < 2; ++half) {
#pragma unroll
        for (int s2 = 0; s2 < 2; ++s2)
#pragma unroll
          for (int r = 0; r < 4; ++r)
            Pw[(g * 4 + r) * 40 + s2 * 16 + fr] = f2bf(p[half * 2 + s2][r]);
        bf16x8 pf = *(const bf16x8*)(&Pw[fr * 40 + g * 8]);
        __builtin_amdgcn_s_setprio(1);
#pragma unroll
        for (int dt = 0; dt < 8; ++dt) {
          const int row = dt * 16 + fr;
          bf16x8 vf = *(const bf16x8*)(&Vts[row * 64 + ((half * 32 + g * 8) ^ ((row & 7) << 3))]);
          acc[dt] = __builtin_amdgcn_mfma_f32_16x16x32_bf16(pf, vf, acc[dt], 0, 0, 0);
        }
        __builtin_amdgcn_s_setprio(0);
      }
    }

    float inv[4];
#pragma unroll
    for (int r = 0; r < 4; ++r) inv[r] = 1.0f / l0[r];
#pragma unroll
    for (int dt = 0; dt < 8; ++dt)
#pragma unroll
      for (int r = 0; r < 4; ++r) {
        const size_t row = (size_t)(b * S_ + qt * 64 + wid * 16 + g * 4 + r);
        outp[row * E_ + h * 128 + dt * 16 + fr] = f2bf(acc[dt][r] * inv[r]);
      }
  }
}

// ---------------- launcher ----------------
extern "C" void kernel_launch(void* const* d_in, const int* in_sizes, int n_in,
                              void* d_out, int out_size, void* d_ws, size_t ws_size,
                              hipStream_t stream) {
  (void)in_sizes; (void)n_in; (void)out_size; (void)ws_size;
  const float* x    = (const float*)d_in[0];
  const float* ln1w = (const float*)d_in[1];
  const float* ln1b = (const float*)d_in[2];
  const float* Wqkv = (const float*)d_in[3];
  const float* Wo   = (const float*)d_in[4];
  const float* ln2w = (const float*)d_in[5];
  const float* ln2b = (const float*)d_in[6];
  const float* W1   = (const float*)d_in[7];
  const float* W2   = (const float*)d_in[8];
  float* out = (float*)d_out;
  char* ws = (char*)d_ws;

  // workspace layout (bytes)
  unsigned short* WqkvT = (unsigned short*)(ws + 0);            // 25,165,824
  unsigned short* WoT   = (unsigned short*)(ws + 25165824);     //  8,388,608
  unsigned short* W1T   = (unsigned short*)(ws + 33554432);     // 33,554,432
  unsigned short* W2T   = (unsigned short*)(ws + 67108864);     // 33,554,432
  unsigned short* qkvb  = (unsigned short*)(ws + 100663296);    // 50,331,648
  unsigned short* vTb   = (unsigned short*)(ws + 150994944);    // 16,777,216
  unsigned short* gbuf  = (unsigned short*)(ws + 100663296);    // 67,108,864 (reuses qkv+vT)
  unsigned short* hbuf  = (unsigned short*)(ws + 167772160);    // 16,777,216 (h / attnout / h2)
  float*          x1    = (float*)         (ws + 184549376);    // 33,554,432

  const dim3 tb(32, 8);
  hipLaunchKernelGGL(transpose_w, dim3(6144 / 32, 2048 / 32), tb, 0, stream, Wqkv, WqkvT, 2048, 6144);
  hipLaunchKernelGGL(transpose_w, dim3(2048 / 32, 2048 / 32), tb, 0, stream, Wo,   WoT,   2048, 2048);
  hipLaunchKernelGGL(transpose_w, dim3(8192 / 32, 2048 / 32), tb, 0, stream, W1,   W1T,   2048, 8192);
  hipLaunchKernelGGL(transpose_w, dim3(2048 / 32, 8192 / 32), tb, 0, stream, W2,   W2T,   8192, 2048);

  hipLaunchKernelGGL(ln_kernel, dim3(T_), dim3(256), 0, stream, x, ln1w, ln1b, hbuf);
  hipLaunchKernelGGL((gemmW<0>), dim3(32 * 24), dim3(256), 0, stream,
                     hbuf, WqkvT, (void*)qkvb, (const float*)nullptr, T_, 6144, 2048);
  hipLaunchKernelGGL(extract_vT, dim3(4, 64, 32), tb, 0, stream, qkvb, vTb);
  hipLaunchKernelGGL(attn_kernel, dim3(S_ / 128, B_ * H_), dim3(256), 0, stream, qkvb, vTb, hbuf);
  hipLaunchKernelGGL((gemm32<2>), dim3(32 * 16), dim3(256), 0, stream,
                     hbuf, WoT, (void*)x1, x, T_, 2048, 2048);
  hipLaunchKernelGGL(ln_kernel, dim3(T_), dim3(256), 0, stream, x1, ln2w, ln2b, hbuf);
  hipLaunchKernelGGL((gemmW<1>), dim3(32 * 32), dim3(256), 0, stream,
                     hbuf, W1T, (void*)gbuf, (const float*)nullptr, T_, 8192, 2048);
  hipLaunchKernelGGL((gemm32<2>), dim3(32 * 16), dim3(256), 0, stream,
                     gbuf, W2T, (void*)out, x1, T_, 2048, 8192);
}

// Round 15
// 714.435 us; speedup vs baseline: 1.1673x; 1.1673x over previous
//
#include <hip/hip_runtime.h>
#include <hip/hip_bf16.h>

#define B_ 2
#define S_ 2048
#define E_ 2048
#define H_ 16
#define D_ 128
#define I_ 8192
#define T_ (B_*S_)

typedef __attribute__((ext_vector_type(8))) short bf16x8;      // 8 bf16 in 4 VGPRs
typedef __attribute__((ext_vector_type(8))) unsigned short us8;
typedef __attribute__((ext_vector_type(4))) float f32x4;
typedef __attribute__((ext_vector_type(16))) float f32x16;

__device__ __forceinline__ unsigned short f2bf(float f) {
  union { float f; unsigned int u; } c; c.f = f;
  unsigned int u = c.u;
  unsigned int r = (u + 0x7fffu + ((u >> 16) & 1u)) >> 16;
  return (unsigned short)r;
}

__device__ __forceinline__ void gload16(const void* g, void* l) {
  __builtin_amdgcn_global_load_lds((const __attribute__((address_space(1))) void*)g,
                                   (__attribute__((address_space(3))) void*)l, 16, 0, 0);
}

// ---------------- weight fp32 (K,N) -> bf16 (N,K) transpose ----------------
__global__ void transpose_w(const float* __restrict__ in, unsigned short* __restrict__ out,
                            int K, int N) {
  __shared__ float tile[32][33];
  const int n0 = blockIdx.x * 32, k0 = blockIdx.y * 32;
  const int tx = threadIdx.x, ty = threadIdx.y;
#pragma unroll
  for (int j = 0; j < 4; ++j) {
    int k = k0 + ty + j * 8;
    tile[ty + j * 8][tx] = in[(size_t)k * N + n0 + tx];
  }
  __syncthreads();
#pragma unroll
  for (int j = 0; j < 4; ++j) {
    int n = n0 + ty + j * 8;
    out[(size_t)n * K + k0 + tx] = f2bf(tile[tx][ty + j * 8]);
  }
}

// ---------------- LayerNorm: fp32 (T,E) -> bf16 (T,E) ----------------
__global__ void ln_kernel(const float* __restrict__ x, const float* __restrict__ w,
                          const float* __restrict__ b, unsigned short* __restrict__ out) {
  const int row = blockIdx.x;
  const int tid = threadIdx.x;
  const int wid = tid >> 6, lane = tid & 63;
  const float4* xr = (const float4*)(x + (size_t)row * E_);
  float4 v0 = xr[tid * 2], v1 = xr[tid * 2 + 1];
  float s  = v0.x + v0.y + v0.z + v0.w + v1.x + v1.y + v1.z + v1.w;
  float sq = v0.x*v0.x + v0.y*v0.y + v0.z*v0.z + v0.w*v0.w
           + v1.x*v1.x + v1.y*v1.y + v1.z*v1.z + v1.w*v1.w;
#pragma unroll
  for (int off = 32; off > 0; off >>= 1) {
    s  += __shfl_xor(s, off);
    sq += __shfl_xor(sq, off);
  }
  __shared__ float red[8];
  if (lane == 0) { red[wid] = s; red[wid + 4] = sq; }
  __syncthreads();
  s  = red[0] + red[1] + red[2] + red[3];
  sq = red[4] + red[5] + red[6] + red[7];
  const float mu  = s * (1.0f / E_);
  const float var = sq * (1.0f / E_) - mu * mu;
  const float rstd = rsqrtf(var + 1e-5f);
  const float4* w4 = (const float4*)w + tid * 2;
  const float4* b4 = (const float4*)b + tid * 2;
  float4 w0 = w4[0], w1 = w4[1], bb0 = b4[0], bb1 = b4[1];
  us8 o;
  o[0] = f2bf((v0.x - mu) * rstd * w0.x + bb0.x);
  o[1] = f2bf((v0.y - mu) * rstd * w0.y + bb0.y);
  o[2] = f2bf((v0.z - mu) * rstd * w0.z + bb0.z);
  o[3] = f2bf((v0.w - mu) * rstd * w0.w + bb0.w);
  o[4] = f2bf((v1.x - mu) * rstd * w1.x + bb1.x);
  o[5] = f2bf((v1.y - mu) * rstd * w1.y + bb1.y);
  o[6] = f2bf((v1.z - mu) * rstd * w1.z + bb1.z);
  o[7] = f2bf((v1.w - mu) * rstd * w1.w + bb1.w);
  *(us8*)(&out[(size_t)row * E_ + tid * 8]) = o;
}

// ---------------- 128x128 GEMM, 32x32x16 MFMA, BK=64 (R9 layout) ----------------
template<int EPI>
__global__ __launch_bounds__(256, 3)
void gemm32(const unsigned short* __restrict__ A,
            const unsigned short* __restrict__ Bt,
            void* __restrict__ Cout,
            const float* __restrict__ resid,
            int M, int N, int K) {
  __shared__ __align__(16) unsigned short As[128 * 64];
  __shared__ __align__(16) unsigned short Bs[128 * 64];
  const int gn = N >> 7;
  const int nwg = (M >> 7) * gn;
  const int cpx = nwg >> 3;
  const int bid = blockIdx.x;
  const int swz = (bid & 7) * cpx + (bid >> 3);
  const int bm = swz / gn, bn = swz % gn;
  const int tid = threadIdx.x;
  const int wid = tid >> 6, lane = tid & 63;
  const int wr = wid >> 1, wc = wid & 1;
  const int r31 = lane & 31, hi = lane >> 5;
  const int rsw = r31 & 7;

  const int trow = tid >> 3;                      // 0..31
  const int tc = (tid & 7) ^ (trow & 7);          // chunk 0..7
  const unsigned short* gA = A  + (size_t)(bm * 128 + trow) * K + tc * 8;
  const unsigned short* gB = Bt + (size_t)(bn * 128 + trow) * K + tc * 8;
  unsigned short* lA = &As[tid * 8];
  unsigned short* lB = &Bs[tid * 8];

  f32x16 acc[2][2] = {};
  const int nk = K >> 6;
  for (int kt = 0; kt < nk; ++kt) {
    __syncthreads();
#pragma unroll
    for (int s = 0; s < 4; ++s) {
      gload16(gA + (size_t)(s * 32) * K, lA + s * 2048);
      gload16(gB + (size_t)(s * 32) * K, lB + s * 2048);
    }
    gA += 64; gB += 64;
    __syncthreads();
#pragma unroll
    for (int ks = 0; ks < 4; ++ks) {
      const int ca = ((ks * 2 + hi) ^ rsw) * 8;   // swizzled chunk offset (shorts)
      bf16x8 a0 = *(const bf16x8*)(&As[(wr * 64 +      r31) * 64 + ca]);
      bf16x8 a1 = *(const bf16x8*)(&As[(wr * 64 + 32 + r31) * 64 + ca]);
      bf16x8 b0 = *(const bf16x8*)(&Bs[(wc * 64 +      r31) * 64 + ca]);
      bf16x8 b1 = *(const bf16x8*)(&Bs[(wc * 64 + 32 + r31) * 64 + ca]);
      acc[0][0] = __builtin_amdgcn_mfma_f32_32x32x16_bf16(a0, b0, acc[0][0], 0, 0, 0);
      acc[0][1] = __builtin_amdgcn_mfma_f32_32x32x16_bf16(a0, b1, acc[0][1], 0, 0, 0);
      acc[1][0] = __builtin_amdgcn_mfma_f32_32x32x16_bf16(a1, b0, acc[1][0], 0, 0, 0);
      acc[1][1] = __builtin_amdgcn_mfma_f32_32x32x16_bf16(a1, b1, acc[1][1], 0, 0, 0);
    }
  }

  const int row0 = bm * 128 + wr * 64;
  const int col0 = bn * 128 + wc * 64;
#pragma unroll
  for (int mt = 0; mt < 2; ++mt) {
#pragma unroll
    for (int nt = 0; nt < 2; ++nt) {
#pragma unroll
      for (int rg = 0; rg < 16; ++rg) {
        const int rl = (rg & 3) + 8 * (rg >> 2) + 4 * hi;
        const int row = row0 + mt * 32 + rl;
        const int col = col0 + nt * 32 + r31;
        const size_t idx = (size_t)row * N + col;
        const float v = acc[mt][nt][rg];
        if constexpr (EPI == 0) {
          ((unsigned short*)Cout)[idx] = f2bf(v);
        } else if constexpr (EPI == 1) {
          const float u = 0.7978845608028654f * (v + 0.044715f * v * v * v);
          const float gel = 0.5f * v * (1.0f + tanhf(u));
          ((unsigned short*)Cout)[idx] = f2bf(gel);
        } else {
          ((float*)Cout)[idx] = v + resid[idx];
        }
      }
    }
  }
}

// ---------------- 128x256 GEMM, 32x32x16 MFMA, BK=64, per-wave 64x128 ----------------
template<int EPI>
__global__ __launch_bounds__(256, 2)
void gemmW(const unsigned short* __restrict__ A,
           const unsigned short* __restrict__ Bt,
           void* __restrict__ Cout,
           const float* __restrict__ resid,
           int M, int N, int K) {
  __shared__ __align__(16) unsigned short As[128 * 64];   // 16 KB
  __shared__ __align__(16) unsigned short Bs[256 * 64];   // 32 KB
  const int gn = N >> 8;
  const int nwg = (M >> 7) * gn;
  const int cpx = nwg >> 3;                 // nwg % 8 == 0 for qkv(768)/W1(1024)
  const int bid = blockIdx.x;
  const int swz = (bid & 7) * cpx + (bid >> 3);
  const int bm = swz / gn, bn = swz % gn;
  const int tid = threadIdx.x;
  const int wid = tid >> 6, lane = tid & 63;
  const int wr = wid >> 1, wc = wid & 1;
  const int r31 = lane & 31, hi = lane >> 5;
  const int rsw = r31 & 7;

  const int trow = tid >> 3;                      // 0..31
  const int tc = (tid & 7) ^ (trow & 7);          // chunk 0..7
  const unsigned short* gA = A  + (size_t)(bm * 128 + trow) * K + tc * 8;
  const unsigned short* gB = Bt + (size_t)(bn * 256 + trow) * K + tc * 8;
  unsigned short* lA = &As[tid * 8];
  unsigned short* lB = &Bs[tid * 8];

  f32x16 acc[2][4] = {};
  const int nk = K >> 6;
  for (int kt = 0; kt < nk; ++kt) {
    __syncthreads();
#pragma unroll
    for (int s = 0; s < 4; ++s)
      gload16(gA + (size_t)(s * 32) * K, lA + s * 2048);
#pragma unroll
    for (int s = 0; s < 8; ++s)
      gload16(gB + (size_t)(s * 32) * K, lB + s * 2048);
    gA += 64; gB += 64;
    __syncthreads();
#pragma unroll
    for (int ks = 0; ks < 4; ++ks) {
      const int ca = ((ks * 2 + hi) ^ rsw) * 8;   // swizzled chunk offset (shorts)
      bf16x8 a0 = *(const bf16x8*)(&As[(wr * 64 +      r31) * 64 + ca]);
      bf16x8 a1 = *(const bf16x8*)(&As[(wr * 64 + 32 + r31) * 64 + ca]);
      bf16x8 bq[4];
#pragma unroll
      for (int nt = 0; nt < 4; ++nt)
        bq[nt] = *(const bf16x8*)(&Bs[(wc * 128 + nt * 32 + r31) * 64 + ca]);
#pragma unroll
      for (int nt = 0; nt < 4; ++nt) {
        acc[0][nt] = __builtin_amdgcn_mfma_f32_32x32x16_bf16(a0, bq[nt], acc[0][nt], 0, 0, 0);
        acc[1][nt] = __builtin_amdgcn_mfma_f32_32x32x16_bf16(a1, bq[nt], acc[1][nt], 0, 0, 0);
      }
    }
  }

  const int row0 = bm * 128 + wr * 64;
  const int col0 = bn * 256 + wc * 128;
#pragma unroll
  for (int mt = 0; mt < 2; ++mt) {
#pragma unroll
    for (int nt = 0; nt < 4; ++nt) {
#pragma unroll
      for (int rg = 0; rg < 16; ++rg) {
        const int rl = (rg & 3) + 8 * (rg >> 2) + 4 * hi;
        const int row = row0 + mt * 32 + rl;
        const int col = col0 + nt * 32 + r31;
        const size_t idx = (size_t)row * N + col;
        const float v = acc[mt][nt][rg];
        if constexpr (EPI == 0) {
          ((unsigned short*)Cout)[idx] = f2bf(v);
        } else if constexpr (EPI == 1) {
          const float u = 0.7978845608028654f * (v + 0.044715f * v * v * v);
          const float gel = 0.5f * v * (1.0f + tanhf(u));
          ((unsigned short*)Cout)[idx] = f2bf(gel);
        } else {
          ((float*)Cout)[idx] = v + resid[idx];
        }
      }
    }
  }
}

// ---------------- extract V^T: qkv (T,6144) -> vT (B,H,D,S) bf16 ----------------
__global__ void extract_vT(const unsigned short* __restrict__ qkv, unsigned short* __restrict__ vT) {
  __shared__ unsigned short tile[32][34];
  const int bh = blockIdx.z;               // b*H + h
  const int b = bh >> 4, h = bh & 15;
  const int s0 = blockIdx.y * 32, d0 = blockIdx.x * 32;
  const int tx = threadIdx.x, ty = threadIdx.y;
#pragma unroll
  for (int j = 0; j < 4; ++j) {
    int s = s0 + ty + j * 8;
    tile[ty + j * 8][tx] = qkv[(size_t)(b * S_ + s) * 6144 + 4096 + h * 128 + d0 + tx];
  }
  __syncthreads();
#pragma unroll
  for (int j = 0; j < 4; ++j) {
    int d = d0 + ty + j * 8;
    vT[((size_t)bh * 128 + d) * 2048 + s0 + tx] = tile[tx][ty + j * 8];
  }
}

// ---------------- causal flash attention, KVBLK=64, balanced pairing ----------------
// R14 post-mortem: (256,3)+defer-max regressed +124us = spill signature (the
// duplicated defer-max branch pushed live regs past the 170 budget). R15:
// SAME defer-max, bound reverted to (256,2) (256-reg budget, spill-free as
// in R12) - isolates bound-vs-branch as the culprit.
__global__ __launch_bounds__(256, 2)
void attn_kernel(const unsigned short* __restrict__ qkv,
                 const unsigned short* __restrict__ vT,
                 unsigned short* __restrict__ outp) {
  __shared__ __align__(16) unsigned short Ks[64 * 128];    // 16 KB, swizzled
  __shared__ __align__(16) unsigned short Vts[128 * 64];   // 16 KB, swizzled
  __shared__ __align__(16) unsigned short Ps[4 * 16 * 40]; // 5 KB, per-wave P tile
  const int bx = blockIdx.x;               // 0..15
  const int bh = blockIdx.y;
  const int b = bh >> 4, h = bh & 15;
  const int tid = threadIdx.x, wid = tid >> 6, lane = tid & 63;
  const int fr = lane & 15, g = lane >> 4;

  const unsigned short* kbase = qkv + (size_t)(b * S_) * 6144 + 2048 + h * 128;
  const unsigned short* vbase = vT + (size_t)bh * 128 * 2048;
  unsigned short* Pw = &Ps[wid * 640];
  const float scale = 0.08838834764831845f;

  us8 kreg[4], vreg[4];
#pragma unroll
  for (int j = 0; j < 4; ++j) {
    const int cc = tid + 256 * j;
    kreg[j] = *(const us8*)(kbase + (size_t)(cc >> 4) * 6144 + (cc & 15) * 8);
    vreg[j] = *(const us8*)(vbase + (size_t)(cc >> 3) * 2048 + (cc & 7) * 8);
  }

  for (int hf = 0; hf < 2; ++hf) {
    const int qt = hf ? (31 - bx) : bx;

    const unsigned short* qptr = qkv + (size_t)(b * S_ + qt * 64 + wid * 16 + fr) * 6144 + h * 128;
    bf16x8 qf[4];
#pragma unroll
    for (int dc = 0; dc < 4; ++dc) qf[dc] = *(const bf16x8*)(qptr + dc * 32 + g * 8);

    float m0[4], l0[4];
#pragma unroll
    for (int r = 0; r < 4; ++r) { m0[r] = -1e30f; l0[r] = 0.0f; }
    f32x4 acc[8] = {};

    for (int kt = 0; kt <= qt; ++kt) {
      __syncthreads();
#pragma unroll
      for (int j = 0; j < 4; ++j) {
        const int cc = tid + 256 * j;
        const int krow = cc >> 4, kcp = cc & 15;
        *(us8*)(&Ks[krow * 128 + ((kcp * 8) ^ ((krow & 7) << 3))]) = kreg[j];
        const int drow = cc >> 3, vcp = cc & 7;
        *(us8*)(&Vts[drow * 64 + ((vcp * 8) ^ ((drow & 7) << 3))]) = vreg[j];
      }
      const int nk = (kt < qt) ? (kt + 1) : (hf == 0 ? 0 : -1);
      if (nk >= 0) {
#pragma unroll
        for (int j = 0; j < 4; ++j) {
          const int cc = tid + 256 * j;
          kreg[j] = *(const us8*)(kbase + (size_t)(nk * 64 + (cc >> 4)) * 6144 + (cc & 15) * 8);
          vreg[j] = *(const us8*)(vbase + (size_t)(cc >> 3) * 2048 + nk * 64 + (cc & 7) * 8);
        }
      }
      __syncthreads();

      f32x4 sc[4] = {};
      __builtin_amdgcn_s_setprio(1);
#pragma unroll
      for (int dc = 0; dc < 4; ++dc) {
#pragma unroll
        for (int sub = 0; sub < 4; ++sub) {
          const int row = sub * 16 + fr;
          bf16x8 kf = *(const bf16x8*)(&Ks[row * 128 + ((dc * 32 + g * 8) ^ ((row & 7) << 3))]);
          sc[sub] = __builtin_amdgcn_mfma_f32_16x16x32_bf16(qf[dc], kf, sc[sub], 0, 0, 0);
        }
      }
      __builtin_amdgcn_s_setprio(0);

      float p[4][4];
      const bool diag = (kt == qt);
#pragma unroll
      for (int sub = 0; sub < 4; ++sub) {
#pragma unroll
        for (int r = 0; r < 4; ++r) {
          float v = sc[sub][r] * scale;
          if (diag && (sub * 16 + fr > wid * 16 + g * 4 + r)) v = -1e30f;
          p[sub][r] = v;
        }
      }

      // row maxes for this tile
      float mx4[4];
      int small = 1;
#pragma unroll
      for (int r = 0; r < 4; ++r) {
        float mx = fmaxf(fmaxf(p[0][r], p[1][r]), fmaxf(p[2][r], p[3][r]));
#pragma unroll
        for (int off = 1; off < 16; off <<= 1) mx = fmaxf(mx, __shfl_xor(mx, off));
        mx4[r] = mx;
        small &= (mx <= m0[r] + 8.0f) ? 1 : 0;
      }
      if (__all(small)) {
        // defer-max: keep old m0, no rescale (P bounded by e^8)
#pragma unroll
        for (int r = 0; r < 4; ++r) {
          float rs = 0.0f;
#pragma unroll
          for (int sub = 0; sub < 4; ++sub) { p[sub][r] = __expf(p[sub][r] - m0[r]); rs += p[sub][r]; }
#pragma unroll
          for (int off = 1; off < 16; off <<= 1) rs += __shfl_xor(rs, off);
          l0[r] += rs;
        }
      } else {
#pragma unroll
        for (int r = 0; r < 4; ++r) {
          const float mn = fmaxf(m0[r], mx4[r]);
          const float corr = __expf(m0[r] - mn);
          m0[r] = mn;
          float rs = 0.0f;
#pragma unroll
          for (int sub = 0; sub < 4; ++sub) { p[sub][r] = __expf(p[sub][r] - mn); rs += p[sub][r]; }
#pragma unroll
          for (int off = 1; off < 16; off <<= 1) rs += __shfl_xor(rs, off);
          l0[r] = l0[r] * corr + rs;
#pragma unroll
          for (int dt = 0; dt < 8; ++dt) acc[dt][r] *= corr;
        }
      }

#pragma unroll
      for (int half = 0; half < 2; ++half) {
#pragma unroll
        for (int s2 = 0; s2 < 2; ++s2)
#pragma unroll
          for (int r = 0; r < 4; ++r)
            Pw[(g * 4 + r) * 40 + s2 * 16 + fr] = f2bf(p[half * 2 + s2][r]);
        bf16x8 pf = *(const bf16x8*)(&Pw[fr * 40 + g * 8]);
        __builtin_amdgcn_s_setprio(1);
#pragma unroll
        for (int dt = 0; dt < 8; ++dt) {
          const int row = dt * 16 + fr;
          bf16x8 vf = *(const bf16x8*)(&Vts[row * 64 + ((half * 32 + g * 8) ^ ((row & 7) << 3))]);
          acc[dt] = __builtin_amdgcn_mfma_f32_16x16x32_bf16(pf, vf, acc[dt], 0, 0, 0);
        }
        __builtin_amdgcn_s_setprio(0);
      }
    }

    float inv[4];
#pragma unroll
    for (int r = 0; r < 4; ++r) inv[r] = 1.0f / l0[r];
#pragma unroll
    for (int dt = 0; dt < 8; ++dt)
#pragma unroll
      for (int r = 0; r < 4; ++r) {
        const size_t row = (size_t)(b * S_ + qt * 64 + wid * 16 + g * 4 + r);
        outp[row * E_ + h * 128 + dt * 16 + fr] = f2bf(acc[dt][r] * inv[r]);
      }
  }
}

// ---------------- launcher ----------------
extern "C" void kernel_launch(void* const* d_in, const int* in_sizes, int n_in,
                              void* d_out, int out_size, void* d_ws, size_t ws_size,
                              hipStream_t stream) {
  (void)in_sizes; (void)n_in; (void)out_size; (void)ws_size;
  const float* x    = (const float*)d_in[0];
  const float* ln1w = (const float*)d_in[1];
  const float* ln1b = (const float*)d_in[2];
  const float* Wqkv = (const float*)d_in[3];
  const float* Wo   = (const float*)d_in[4];
  const float* ln2w = (const float*)d_in[5];
  const float* ln2b = (const float*)d_in[6];
  const float* W1   = (const float*)d_in[7];
  const float* W2   = (const float*)d_in[8];
  float* out = (float*)d_out;
  char* ws = (char*)d_ws;

  // workspace layout (bytes)
  unsigned short* WqkvT = (unsigned short*)(ws + 0);            // 25,165,824
  unsigned short* WoT   = (unsigned short*)(ws + 25165824);     //  8,388,608
  unsigned short* W1T   = (unsigned short*)(ws + 33554432);     // 33,554,432
  unsigned short* W2T   = (unsigned short*)(ws + 67108864);     // 33,554,432
  unsigned short* qkvb  = (unsigned short*)(ws + 100663296);    // 50,331,648
  unsigned short* vTb   = (unsigned short*)(ws + 150994944);    // 16,777,216
  unsigned short* gbuf  = (unsigned short*)(ws + 100663296);    // 67,108,864 (reuses qkv+vT)
  unsigned short* hbuf  = (unsigned short*)(ws + 167772160);    // 16,777,216 (h / attnout / h2)
  float*          x1    = (float*)         (ws + 184549376);    // 33,554,432

  const dim3 tb(32, 8);
  hipLaunchKernelGGL(transpose_w, dim3(6144 / 32, 2048 / 32), tb, 0, stream, Wqkv, WqkvT, 2048, 6144);
  hipLaunchKernelGGL(transpose_w, dim3(2048 / 32, 2048 / 32), tb, 0, stream, Wo,   WoT,   2048, 2048);
  hipLaunchKernelGGL(transpose_w, dim3(8192 / 32, 2048 / 32), tb, 0, stream, W1,   W1T,   2048, 8192);
  hipLaunchKernelGGL(transpose_w, dim3(2048 / 32, 8192 / 32), tb, 0, stream, W2,   W2T,   8192, 2048);

  hipLaunchKernelGGL(ln_kernel, dim3(T_), dim3(256), 0, stream, x, ln1w, ln1b, hbuf);
  hipLaunchKernelGGL((gemmW<0>), dim3(32 * 24), dim3(256), 0, stream,
                     hbuf, WqkvT, (void*)qkvb, (const float*)nullptr, T_, 6144, 2048);
  hipLaunchKernelGGL(extract_vT, dim3(4, 64, 32), tb, 0, stream, qkvb, vTb);
  hipLaunchKernelGGL(attn_kernel, dim3(S_ / 128, B_ * H_), dim3(256), 0, stream, qkvb, vTb, hbuf);
  hipLaunchKernelGGL((gemm32<2>), dim3(32 * 16), dim3(256), 0, stream,
                     hbuf, WoT, (void*)x1, x, T_, 2048, 2048);
  hipLaunchKernelGGL(ln_kernel, dim3(T_), dim3(256), 0, stream, x1, ln2w, ln2b, hbuf);
  hipLaunchKernelGGL((gemmW<1>), dim3(32 * 32), dim3(256), 0, stream,
                     hbuf, W1T, (void*)gbuf, (const float*)nullptr, T_, 8192, 2048);
  hipLaunchKernelGGL((gemm32<2>), dim3(32 * 16), dim3(256), 0, stream,
                     gbuf, W2T, (void*)out, x1, T_, 2048, 8192);
}

// Round 16
// 705.286 us; speedup vs baseline: 1.1824x; 1.0130x over previous
//
#include <hip/hip_runtime.h>
#include <hip/hip_bf16.h>

#define B_ 2
#define S_ 2048
#define E_ 2048
#define H_ 16
#define D_ 128
#define I_ 8192
#define T_ (B_*S_)

typedef __attribute__((ext_vector_type(8))) short bf16x8;      // 8 bf16 in 4 VGPRs
typedef __attribute__((ext_vector_type(8))) unsigned short us8;
typedef __attribute__((ext_vector_type(4))) float f32x4;
typedef __attribute__((ext_vector_type(16))) float f32x16;

__device__ __forceinline__ unsigned short f2bf(float f) {
  union { float f; unsigned int u; } c; c.f = f;
  unsigned int u = c.u;
  unsigned int r = (u + 0x7fffu + ((u >> 16) & 1u)) >> 16;
  return (unsigned short)r;
}

__device__ __forceinline__ void gload16(const void* g, void* l) {
  __builtin_amdgcn_global_load_lds((const __attribute__((address_space(1))) void*)g,
                                   (__attribute__((address_space(3))) void*)l, 16, 0, 0);
}

// ---------------- weight fp32 (K,N) -> bf16 (N,K) transpose ----------------
__global__ void transpose_w(const float* __restrict__ in, unsigned short* __restrict__ out,
                            int K, int N) {
  __shared__ float tile[32][33];
  const int n0 = blockIdx.x * 32, k0 = blockIdx.y * 32;
  const int tx = threadIdx.x, ty = threadIdx.y;
#pragma unroll
  for (int j = 0; j < 4; ++j) {
    int k = k0 + ty + j * 8;
    tile[ty + j * 8][tx] = in[(size_t)k * N + n0 + tx];
  }
  __syncthreads();
#pragma unroll
  for (int j = 0; j < 4; ++j) {
    int n = n0 + ty + j * 8;
    out[(size_t)n * K + k0 + tx] = f2bf(tile[tx][ty + j * 8]);
  }
}

// ---------------- LayerNorm: fp32 (T,E) -> bf16 (T,E) ----------------
__global__ void ln_kernel(const float* __restrict__ x, const float* __restrict__ w,
                          const float* __restrict__ b, unsigned short* __restrict__ out) {
  const int row = blockIdx.x;
  const int tid = threadIdx.x;
  const int wid = tid >> 6, lane = tid & 63;
  const float4* xr = (const float4*)(x + (size_t)row * E_);
  float4 v0 = xr[tid * 2], v1 = xr[tid * 2 + 1];
  float s  = v0.x + v0.y + v0.z + v0.w + v1.x + v1.y + v1.z + v1.w;
  float sq = v0.x*v0.x + v0.y*v0.y + v0.z*v0.z + v0.w*v0.w
           + v1.x*v1.x + v1.y*v1.y + v1.z*v1.z + v1.w*v1.w;
#pragma unroll
  for (int off = 32; off > 0; off >>= 1) {
    s  += __shfl_xor(s, off);
    sq += __shfl_xor(sq, off);
  }
  __shared__ float red[8];
  if (lane == 0) { red[wid] = s; red[wid + 4] = sq; }
  __syncthreads();
  s  = red[0] + red[1] + red[2] + red[3];
  sq = red[4] + red[5] + red[6] + red[7];
  const float mu  = s * (1.0f / E_);
  const float var = sq * (1.0f / E_) - mu * mu;
  const float rstd = rsqrtf(var + 1e-5f);
  const float4* w4 = (const float4*)w + tid * 2;
  const float4* b4 = (const float4*)b + tid * 2;
  float4 w0 = w4[0], w1 = w4[1], bb0 = b4[0], bb1 = b4[1];
  us8 o;
  o[0] = f2bf((v0.x - mu) * rstd * w0.x + bb0.x);
  o[1] = f2bf((v0.y - mu) * rstd * w0.y + bb0.y);
  o[2] = f2bf((v0.z - mu) * rstd * w0.z + bb0.z);
  o[3] = f2bf((v0.w - mu) * rstd * w0.w + bb0.w);
  o[4] = f2bf((v1.x - mu) * rstd * w1.x + bb1.x);
  o[5] = f2bf((v1.y - mu) * rstd * w1.y + bb1.y);
  o[6] = f2bf((v1.z - mu) * rstd * w1.z + bb1.z);
  o[7] = f2bf((v1.w - mu) * rstd * w1.w + bb1.w);
  *(us8*)(&out[(size_t)row * E_ + tid * 8]) = o;
}

// ---------------- 128x128 GEMM, 32x32x16 MFMA, BK=64 (R9 layout) ----------------
// R16: 2D-grouped XCD block order. Old decode (bm=swz/gn) made co-resident
// blocks span the FULL B panel (32MB >> 4MB per-XCD L2) -> FETCH 5-6x ideal,
// staging loads miss L2, latency exposed. New: bn in groups of 8, bm-major
// inside -> co-resident set spans <=8bm x 8bn (~12MB), B-reuse x8.
template<int EPI>
__global__ __launch_bounds__(256, 3)
void gemm32(const unsigned short* __restrict__ A,
            const unsigned short* __restrict__ Bt,
            void* __restrict__ Cout,
            const float* __restrict__ resid,
            int M, int N, int K) {
  __shared__ __align__(16) unsigned short As[128 * 64];
  __shared__ __align__(16) unsigned short Bs[128 * 64];
  const int gm = M >> 7;
  const int gn = N >> 7;                    // gn % 8 == 0 for all our shapes
  const int nwg = gm * gn;
  const int cpx = nwg >> 3;
  const int bid = blockIdx.x;
  const int swz = (bid & 7) * cpx + (bid >> 3);
  const int cg = swz / (gm << 3);
  const int rr = swz - cg * (gm << 3);
  const int bm = rr >> 3;
  const int bn = (cg << 3) + (rr & 7);
  const int tid = threadIdx.x;
  const int wid = tid >> 6, lane = tid & 63;
  const int wr = wid >> 1, wc = wid & 1;
  const int r31 = lane & 31, hi = lane >> 5;
  const int rsw = r31 & 7;

  const int trow = tid >> 3;                      // 0..31
  const int tc = (tid & 7) ^ (trow & 7);          // chunk 0..7
  const unsigned short* gA = A  + (size_t)(bm * 128 + trow) * K + tc * 8;
  const unsigned short* gB = Bt + (size_t)(bn * 128 + trow) * K + tc * 8;
  unsigned short* lA = &As[tid * 8];
  unsigned short* lB = &Bs[tid * 8];

  f32x16 acc[2][2] = {};
  const int nk = K >> 6;
  for (int kt = 0; kt < nk; ++kt) {
    __syncthreads();
#pragma unroll
    for (int s = 0; s < 4; ++s) {
      gload16(gA + (size_t)(s * 32) * K, lA + s * 2048);
      gload16(gB + (size_t)(s * 32) * K, lB + s * 2048);
    }
    gA += 64; gB += 64;
    __syncthreads();
#pragma unroll
    for (int ks = 0; ks < 4; ++ks) {
      const int ca = ((ks * 2 + hi) ^ rsw) * 8;   // swizzled chunk offset (shorts)
      bf16x8 a0 = *(const bf16x8*)(&As[(wr * 64 +      r31) * 64 + ca]);
      bf16x8 a1 = *(const bf16x8*)(&As[(wr * 64 + 32 + r31) * 64 + ca]);
      bf16x8 b0 = *(const bf16x8*)(&Bs[(wc * 64 +      r31) * 64 + ca]);
      bf16x8 b1 = *(const bf16x8*)(&Bs[(wc * 64 + 32 + r31) * 64 + ca]);
      acc[0][0] = __builtin_amdgcn_mfma_f32_32x32x16_bf16(a0, b0, acc[0][0], 0, 0, 0);
      acc[0][1] = __builtin_amdgcn_mfma_f32_32x32x16_bf16(a0, b1, acc[0][1], 0, 0, 0);
      acc[1][0] = __builtin_amdgcn_mfma_f32_32x32x16_bf16(a1, b0, acc[1][0], 0, 0, 0);
      acc[1][1] = __builtin_amdgcn_mfma_f32_32x32x16_bf16(a1, b1, acc[1][1], 0, 0, 0);
    }
  }

  const int row0 = bm * 128 + wr * 64;
  const int col0 = bn * 128 + wc * 64;
#pragma unroll
  for (int mt = 0; mt < 2; ++mt) {
#pragma unroll
    for (int nt = 0; nt < 2; ++nt) {
#pragma unroll
      for (int rg = 0; rg < 16; ++rg) {
        const int rl = (rg & 3) + 8 * (rg >> 2) + 4 * hi;
        const int row = row0 + mt * 32 + rl;
        const int col = col0 + nt * 32 + r31;
        const size_t idx = (size_t)row * N + col;
        const float v = acc[mt][nt][rg];
        if constexpr (EPI == 0) {
          ((unsigned short*)Cout)[idx] = f2bf(v);
        } else if constexpr (EPI == 1) {
          const float u = 0.7978845608028654f * (v + 0.044715f * v * v * v);
          const float gel = 0.5f * v * (1.0f + tanhf(u));
          ((unsigned short*)Cout)[idx] = f2bf(gel);
        } else {
          ((float*)Cout)[idx] = v + resid[idx];
        }
      }
    }
  }
}

// ---------------- 128x256 GEMM, 32x32x16 MFMA, BK=64, per-wave 64x128 ----------------
// R16: same 2D-grouped XCD block order as gemm32 (see comment there).
template<int EPI>
__global__ __launch_bounds__(256, 2)
void gemmW(const unsigned short* __restrict__ A,
           const unsigned short* __restrict__ Bt,
           void* __restrict__ Cout,
           const float* __restrict__ resid,
           int M, int N, int K) {
  __shared__ __align__(16) unsigned short As[128 * 64];   // 16 KB
  __shared__ __align__(16) unsigned short Bs[256 * 64];   // 32 KB
  const int gm = M >> 7;
  const int gn = N >> 8;                    // gn % 8 == 0 for qkv(24)/W1(32)
  const int nwg = gm * gn;
  const int cpx = nwg >> 3;
  const int bid = blockIdx.x;
  const int swz = (bid & 7) * cpx + (bid >> 3);
  const int cg = swz / (gm << 3);
  const int rr = swz - cg * (gm << 3);
  const int bm = rr >> 3;
  const int bn = (cg << 3) + (rr & 7);
  const int tid = threadIdx.x;
  const int wid = tid >> 6, lane = tid & 63;
  const int wr = wid >> 1, wc = wid & 1;
  const int r31 = lane & 31, hi = lane >> 5;
  const int rsw = r31 & 7;

  const int trow = tid >> 3;                      // 0..31
  const int tc = (tid & 7) ^ (trow & 7);          // chunk 0..7
  const unsigned short* gA = A  + (size_t)(bm * 128 + trow) * K + tc * 8;
  const unsigned short* gB = Bt + (size_t)(bn * 256 + trow) * K + tc * 8;
  unsigned short* lA = &As[tid * 8];
  unsigned short* lB = &Bs[tid * 8];

  f32x16 acc[2][4] = {};
  const int nk = K >> 6;
  for (int kt = 0; kt < nk; ++kt) {
    __syncthreads();
#pragma unroll
    for (int s = 0; s < 4; ++s)
      gload16(gA + (size_t)(s * 32) * K, lA + s * 2048);
#pragma unroll
    for (int s = 0; s < 8; ++s)
      gload16(gB + (size_t)(s * 32) * K, lB + s * 2048);
    gA += 64; gB += 64;
    __syncthreads();
#pragma unroll
    for (int ks = 0; ks < 4; ++ks) {
      const int ca = ((ks * 2 + hi) ^ rsw) * 8;   // swizzled chunk offset (shorts)
      bf16x8 a0 = *(const bf16x8*)(&As[(wr * 64 +      r31) * 64 + ca]);
      bf16x8 a1 = *(const bf16x8*)(&As[(wr * 64 + 32 + r31) * 64 + ca]);
      bf16x8 bq[4];
#pragma unroll
      for (int nt = 0; nt < 4; ++nt)
        bq[nt] = *(const bf16x8*)(&Bs[(wc * 128 + nt * 32 + r31) * 64 + ca]);
#pragma unroll
      for (int nt = 0; nt < 4; ++nt) {
        acc[0][nt] = __builtin_amdgcn_mfma_f32_32x32x16_bf16(a0, bq[nt], acc[0][nt], 0, 0, 0);
        acc[1][nt] = __builtin_amdgcn_mfma_f32_32x32x16_bf16(a1, bq[nt], acc[1][nt], 0, 0, 0);
      }
    }
  }

  const int row0 = bm * 128 + wr * 64;
  const int col0 = bn * 256 + wc * 128;
#pragma unroll
  for (int mt = 0; mt < 2; ++mt) {
#pragma unroll
    for (int nt = 0; nt < 4; ++nt) {
#pragma unroll
      for (int rg = 0; rg < 16; ++rg) {
        const int rl = (rg & 3) + 8 * (rg >> 2) + 4 * hi;
        const int row = row0 + mt * 32 + rl;
        const int col = col0 + nt * 32 + r31;
        const size_t idx = (size_t)row * N + col;
        const float v = acc[mt][nt][rg];
        if constexpr (EPI == 0) {
          ((unsigned short*)Cout)[idx] = f2bf(v);
        } else if constexpr (EPI == 1) {
          const float u = 0.7978845608028654f * (v + 0.044715f * v * v * v);
          const float gel = 0.5f * v * (1.0f + tanhf(u));
          ((unsigned short*)Cout)[idx] = f2bf(gel);
        } else {
          ((float*)Cout)[idx] = v + resid[idx];
        }
      }
    }
  }
}

// ---------------- extract V^T: qkv (T,6144) -> vT (B,H,D,S) bf16 ----------------
__global__ void extract_vT(const unsigned short* __restrict__ qkv, unsigned short* __restrict__ vT) {
  __shared__ unsigned short tile[32][34];
  const int bh = blockIdx.z;               // b*H + h
  const int b = bh >> 4, h = bh & 15;
  const int s0 = blockIdx.y * 32, d0 = blockIdx.x * 32;
  const int tx = threadIdx.x, ty = threadIdx.y;
#pragma unroll
  for (int j = 0; j < 4; ++j) {
    int s = s0 + ty + j * 8;
    tile[ty + j * 8][tx] = qkv[(size_t)(b * S_ + s) * 6144 + 4096 + h * 128 + d0 + tx];
  }
  __syncthreads();
#pragma unroll
  for (int j = 0; j < 4; ++j) {
    int d = d0 + ty + j * 8;
    vT[((size_t)bh * 128 + d) * 2048 + s0 + tx] = tile[tx][ty + j * 8];
  }
}

// ---------------- causal flash attention, KVBLK=64, balanced pairing ----------------
// (identical to R15: (256,2), defer-max, balanced q-tile pairing)
__global__ __launch_bounds__(256, 2)
void attn_kernel(const unsigned short* __restrict__ qkv,
                 const unsigned short* __restrict__ vT,
                 unsigned short* __restrict__ outp) {
  __shared__ __align__(16) unsigned short Ks[64 * 128];    // 16 KB, swizzled
  __shared__ __align__(16) unsigned short Vts[128 * 64];   // 16 KB, swizzled
  __shared__ __align__(16) unsigned short Ps[4 * 16 * 40]; // 5 KB, per-wave P tile
  const int bx = blockIdx.x;               // 0..15
  const int bh = blockIdx.y;
  const int b = bh >> 4, h = bh & 15;
  const int tid = threadIdx.x, wid = tid >> 6, lane = tid & 63;
  const int fr = lane & 15, g = lane >> 4;

  const unsigned short* kbase = qkv + (size_t)(b * S_) * 6144 + 2048 + h * 128;
  const unsigned short* vbase = vT + (size_t)bh * 128 * 2048;
  unsigned short* Pw = &Ps[wid * 640];
  const float scale = 0.08838834764831845f;

  us8 kreg[4], vreg[4];
#pragma unroll
  for (int j = 0; j < 4; ++j) {
    const int cc = tid + 256 * j;
    kreg[j] = *(const us8*)(kbase + (size_t)(cc >> 4) * 6144 + (cc & 15) * 8);
    vreg[j] = *(const us8*)(vbase + (size_t)(cc >> 3) * 2048 + (cc & 7) * 8);
  }

  for (int hf = 0; hf < 2; ++hf) {
    const int qt = hf ? (31 - bx) : bx;

    const unsigned short* qptr = qkv + (size_t)(b * S_ + qt * 64 + wid * 16 + fr) * 6144 + h * 128;
    bf16x8 qf[4];
#pragma unroll
    for (int dc = 0; dc < 4; ++dc) qf[dc] = *(const bf16x8*)(qptr + dc * 32 + g * 8);

    float m0[4], l0[4];
#pragma unroll
    for (int r = 0; r < 4; ++r) { m0[r] = -1e30f; l0[r] = 0.0f; }
    f32x4 acc[8] = {};

    for (int kt = 0; kt <= qt; ++kt) {
      __syncthreads();
#pragma unroll
      for (int j = 0; j < 4; ++j) {
        const int cc = tid + 256 * j;
        const int krow = cc >> 4, kcp = cc & 15;
        *(us8*)(&Ks[krow * 128 + ((kcp * 8) ^ ((krow & 7) << 3))]) = kreg[j];
        const int drow = cc >> 3, vcp = cc & 7;
        *(us8*)(&Vts[drow * 64 + ((vcp * 8) ^ ((drow & 7) << 3))]) = vreg[j];
      }
      const int nk = (kt < qt) ? (kt + 1) : (hf == 0 ? 0 : -1);
      if (nk >= 0) {
#pragma unroll
        for (int j = 0; j < 4; ++j) {
          const int cc = tid + 256 * j;
          kreg[j] = *(const us8*)(kbase + (size_t)(nk * 64 + (cc >> 4)) * 6144 + (cc & 15) * 8);
          vreg[j] = *(const us8*)(vbase + (size_t)(cc >> 3) * 2048 + nk * 64 + (cc & 7) * 8);
        }
      }
      __syncthreads();

      f32x4 sc[4] = {};
      __builtin_amdgcn_s_setprio(1);
#pragma unroll
      for (int dc = 0; dc < 4; ++dc) {
#pragma unroll
        for (int sub = 0; sub < 4; ++sub) {
          const int row = sub * 16 + fr;
          bf16x8 kf = *(const bf16x8*)(&Ks[row * 128 + ((dc * 32 + g * 8) ^ ((row & 7) << 3))]);
          sc[sub] = __builtin_amdgcn_mfma_f32_16x16x32_bf16(qf[dc], kf, sc[sub], 0, 0, 0);
        }
      }
      __builtin_amdgcn_s_setprio(0);

      float p[4][4];
      const bool diag = (kt == qt);
#pragma unroll
      for (int sub = 0; sub < 4; ++sub) {
#pragma unroll
        for (int r = 0; r < 4; ++r) {
          float v = sc[sub][r] * scale;
          if (diag && (sub * 16 + fr > wid * 16 + g * 4 + r)) v = -1e30f;
          p[sub][r] = v;
        }
      }

      // row maxes for this tile
      float mx4[4];
      int small = 1;
#pragma unroll
      for (int r = 0; r < 4; ++r) {
        float mx = fmaxf(fmaxf(p[0][r], p[1][r]), fmaxf(p[2][r], p[3][r]));
#pragma unroll
        for (int off = 1; off < 16; off <<= 1) mx = fmaxf(mx, __shfl_xor(mx, off));
        mx4[r] = mx;
        small &= (mx <= m0[r] + 8.0f) ? 1 : 0;
      }
      if (__all(small)) {
        // defer-max: keep old m0, no rescale (P bounded by e^8)
#pragma unroll
        for (int r = 0; r < 4; ++r) {
          float rs = 0.0f;
#pragma unroll
          for (int sub = 0; sub < 4; ++sub) { p[sub][r] = __expf(p[sub][r] - m0[r]); rs += p[sub][r]; }
#pragma unroll
          for (int off = 1; off < 16; off <<= 1) rs += __shfl_xor(rs, off);
          l0[r] += rs;
        }
      } else {
#pragma unroll
        for (int r = 0; r < 4; ++r) {
          const float mn = fmaxf(m0[r], mx4[r]);
          const float corr = __expf(m0[r] - mn);
          m0[r] = mn;
          float rs = 0.0f;
#pragma unroll
          for (int sub = 0; sub < 4; ++sub) { p[sub][r] = __expf(p[sub][r] - mn); rs += p[sub][r]; }
#pragma unroll
          for (int off = 1; off < 16; off <<= 1) rs += __shfl_xor(rs, off);
          l0[r] = l0[r] * corr + rs;
#pragma unroll
          for (int dt = 0; dt < 8; ++dt) acc[dt][r] *= corr;
        }
      }

#pragma unroll
      for (int half = 0; half < 2; ++half) {
#pragma unroll
        for (int s2 = 0; s2 < 2; ++s2)
#pragma unroll
          for (int r = 0; r < 4; ++r)
            Pw[(g * 4 + r) * 40 + s2 * 16 + fr] = f2bf(p[half * 2 + s2][r]);
        bf16x8 pf = *(const bf16x8*)(&Pw[fr * 40 + g * 8]);
        __builtin_amdgcn_s_setprio(1);
#pragma unroll
        for (int dt = 0; dt < 8; ++dt) {
          const int row = dt * 16 + fr;
          bf16x8 vf = *(const bf16x8*)(&Vts[row * 64 + ((half * 32 + g * 8) ^ ((row & 7) << 3))]);
          acc[dt] = __builtin_amdgcn_mfma_f32_16x16x32_bf16(pf, vf, acc[dt], 0, 0, 0);
        }
        __builtin_amdgcn_s_setprio(0);
      }
    }

    float inv[4];
#pragma unroll
    for (int r = 0; r < 4; ++r) inv[r] = 1.0f / l0[r];
#pragma unroll
    for (int dt = 0; dt < 8; ++dt)
#pragma unroll
      for (int r = 0; r < 4; ++r) {
        const size_t row = (size_t)(b * S_ + qt * 64 + wid * 16 + g * 4 + r);
        outp[row * E_ + h * 128 + dt * 16 + fr] = f2bf(acc[dt][r] * inv[r]);
      }
  }
}

// ---------------- launcher ----------------
extern "C" void kernel_launch(void* const* d_in, const int* in_sizes, int n_in,
                              void* d_out, int out_size, void* d_ws, size_t ws_size,
                              hipStream_t stream) {
  (void)in_sizes; (void)n_in; (void)out_size; (void)ws_size;
  const float* x    = (const float*)d_in[0];
  const float* ln1w = (const float*)d_in[1];
  const float* ln1b = (const float*)d_in[2];
  const float* Wqkv = (const float*)d_in[3];
  const float* Wo   = (const float*)d_in[4];
  const float* ln2w = (const float*)d_in[5];
  const float* ln2b = (const float*)d_in[6];
  const float* W1   = (const float*)d_in[7];
  const float* W2   = (const float*)d_in[8];
  float* out = (float*)d_out;
  char* ws = (char*)d_ws;

  // workspace layout (bytes)
  unsigned short* WqkvT = (unsigned short*)(ws + 0);            // 25,165,824
  unsigned short* WoT   = (unsigned short*)(ws + 25165824);     //  8,388,608
  unsigned short* W1T   = (unsigned short*)(ws + 33554432);     // 33,554,432
  unsigned short* W2T   = (unsigned short*)(ws + 67108864);     // 33,554,432
  unsigned short* qkvb  = (unsigned short*)(ws + 100663296);    // 50,331,648
  unsigned short* vTb   = (unsigned short*)(ws + 150994944);    // 16,777,216
  unsigned short* gbuf  = (unsigned short*)(ws + 100663296);    // 67,108,864 (reuses qkv+vT)
  unsigned short* hbuf  = (unsigned short*)(ws + 167772160);    // 16,777,216 (h / attnout / h2)
  float*          x1    = (float*)         (ws + 184549376);    // 33,554,432

  const dim3 tb(32, 8);
  hipLaunchKernelGGL(transpose_w, dim3(6144 / 32, 2048 / 32), tb, 0, stream, Wqkv, WqkvT, 2048, 6144);
  hipLaunchKernelGGL(transpose_w, dim3(2048 / 32, 2048 / 32), tb, 0, stream, Wo,   WoT,   2048, 2048);
  hipLaunchKernelGGL(transpose_w, dim3(8192 / 32, 2048 / 32), tb, 0, stream, W1,   W1T,   2048, 8192);
  hipLaunchKernelGGL(transpose_w, dim3(2048 / 32, 8192 / 32), tb, 0, stream, W2,   W2T,   8192, 2048);

  hipLaunchKernelGGL(ln_kernel, dim3(T_), dim3(256), 0, stream, x, ln1w, ln1b, hbuf);
  hipLaunchKernelGGL((gemmW<0>), dim3(32 * 24), dim3(256), 0, stream,
                     hbuf, WqkvT, (void*)qkvb, (const float*)nullptr, T_, 6144, 2048);
  hipLaunchKernelGGL(extract_vT, dim3(4, 64, 32), tb, 0, stream, qkvb, vTb);
  hipLaunchKernelGGL(attn_kernel, dim3(S_ / 128, B_ * H_), dim3(256), 0, stream, qkvb, vTb, hbuf);
  hipLaunchKernelGGL((gemm32<2>), dim3(32 * 16), dim3(256), 0, stream,
                     hbuf, WoT, (void*)x1, x, T_, 2048, 2048);
  hipLaunchKernelGGL(ln_kernel, dim3(T_), dim3(256), 0, stream, x1, ln2w, ln2b, hbuf);
  hipLaunchKernelGGL((gemmW<1>), dim3(32 * 32), dim3(256), 0, stream,
                     hbuf, W1T, (void*)gbuf, (const float*)nullptr, T_, 8192, 2048);
  hipLaunchKernelGGL((gemm32<2>), dim3(32 * 16), dim3(256), 0, stream,
                     gbuf, W2T, (void*)out, x1, T_, 2048, 8192);
}

// Round 17
// 680.569 us; speedup vs baseline: 1.2254x; 1.0363x over previous
//
#include <hip/hip_runtime.h>
#include <hip/hip_bf16.h>

#define B_ 2
#define S_ 2048
#define E_ 2048
#define H_ 16
#define D_ 128
#define I_ 8192
#define T_ (B_*S_)

typedef __attribute__((ext_vector_type(8))) short bf16x8;      // 8 bf16 in 4 VGPRs
typedef __attribute__((ext_vector_type(8))) unsigned short us8;
typedef __attribute__((ext_vector_type(4))) float f32x4;
typedef __attribute__((ext_vector_type(16))) float f32x16;

__device__ __forceinline__ unsigned short f2bf(float f) {
  union { float f; unsigned int u; } c; c.f = f;
  unsigned int u = c.u;
  unsigned int r = (u + 0x7fffu + ((u >> 16) & 1u)) >> 16;
  return (unsigned short)r;
}

__device__ __forceinline__ void gload16(const void* g, void* l) {
  __builtin_amdgcn_global_load_lds((const __attribute__((address_space(1))) void*)g,
                                   (__attribute__((address_space(3))) void*)l, 16, 0, 0);
}

// ---------------- weight fp32 (K,N) -> bf16 (N,K) transpose ----------------
__global__ void transpose_w(const float* __restrict__ in, unsigned short* __restrict__ out,
                            int K, int N) {
  __shared__ float tile[32][33];
  const int n0 = blockIdx.x * 32, k0 = blockIdx.y * 32;
  const int tx = threadIdx.x, ty = threadIdx.y;
#pragma unroll
  for (int j = 0; j < 4; ++j) {
    int k = k0 + ty + j * 8;
    tile[ty + j * 8][tx] = in[(size_t)k * N + n0 + tx];
  }
  __syncthreads();
#pragma unroll
  for (int j = 0; j < 4; ++j) {
    int n = n0 + ty + j * 8;
    out[(size_t)n * K + k0 + tx] = f2bf(tile[tx][ty + j * 8]);
  }
}

// ---------------- LayerNorm: fp32 (T,E) -> bf16 (T,E) ----------------
__global__ void ln_kernel(const float* __restrict__ x, const float* __restrict__ w,
                          const float* __restrict__ b, unsigned short* __restrict__ out) {
  const int row = blockIdx.x;
  const int tid = threadIdx.x;
  const int wid = tid >> 6, lane = tid & 63;
  const float4* xr = (const float4*)(x + (size_t)row * E_);
  float4 v0 = xr[tid * 2], v1 = xr[tid * 2 + 1];
  float s  = v0.x + v0.y + v0.z + v0.w + v1.x + v1.y + v1.z + v1.w;
  float sq = v0.x*v0.x + v0.y*v0.y + v0.z*v0.z + v0.w*v0.w
           + v1.x*v1.x + v1.y*v1.y + v1.z*v1.z + v1.w*v1.w;
#pragma unroll
  for (int off = 32; off > 0; off >>= 1) {
    s  += __shfl_xor(s, off);
    sq += __shfl_xor(sq, off);
  }
  __shared__ float red[8];
  if (lane == 0) { red[wid] = s; red[wid + 4] = sq; }
  __syncthreads();
  s  = red[0] + red[1] + red[2] + red[3];
  sq = red[4] + red[5] + red[6] + red[7];
  const float mu  = s * (1.0f / E_);
  const float var = sq * (1.0f / E_) - mu * mu;
  const float rstd = rsqrtf(var + 1e-5f);
  const float4* w4 = (const float4*)w + tid * 2;
  const float4* b4 = (const float4*)b + tid * 2;
  float4 w0 = w4[0], w1 = w4[1], bb0 = b4[0], bb1 = b4[1];
  us8 o;
  o[0] = f2bf((v0.x - mu) * rstd * w0.x + bb0.x);
  o[1] = f2bf((v0.y - mu) * rstd * w0.y + bb0.y);
  o[2] = f2bf((v0.z - mu) * rstd * w0.z + bb0.z);
  o[3] = f2bf((v0.w - mu) * rstd * w0.w + bb0.w);
  o[4] = f2bf((v1.x - mu) * rstd * w1.x + bb1.x);
  o[5] = f2bf((v1.y - mu) * rstd * w1.y + bb1.y);
  o[6] = f2bf((v1.z - mu) * rstd * w1.z + bb1.z);
  o[7] = f2bf((v1.w - mu) * rstd * w1.w + bb1.w);
  *(us8*)(&out[(size_t)row * E_ + tid * 8]) = o;
}

// ---------------- 128x128 GEMM, 32x32x16 MFMA, BK=64 (R9 layout, R16 swizzle) ----------------
template<int EPI>
__global__ __launch_bounds__(256, 3)
void gemm32(const unsigned short* __restrict__ A,
            const unsigned short* __restrict__ Bt,
            void* __restrict__ Cout,
            const float* __restrict__ resid,
            int M, int N, int K) {
  __shared__ __align__(16) unsigned short As[128 * 64];
  __shared__ __align__(16) unsigned short Bs[128 * 64];
  const int gm = M >> 7;
  const int gn = N >> 7;
  const int nwg = gm * gn;
  const int cpx = nwg >> 3;
  const int bid = blockIdx.x;
  const int swz = (bid & 7) * cpx + (bid >> 3);
  const int cg = swz / (gm << 3);
  const int rr = swz - cg * (gm << 3);
  const int bm = rr >> 3;
  const int bn = (cg << 3) + (rr & 7);
  const int tid = threadIdx.x;
  const int wid = tid >> 6, lane = tid & 63;
  const int wr = wid >> 1, wc = wid & 1;
  const int r31 = lane & 31, hi = lane >> 5;
  const int rsw = r31 & 7;

  const int trow = tid >> 3;                      // 0..31
  const int tc = (tid & 7) ^ (trow & 7);          // chunk 0..7
  const unsigned short* gA = A  + (size_t)(bm * 128 + trow) * K + tc * 8;
  const unsigned short* gB = Bt + (size_t)(bn * 128 + trow) * K + tc * 8;
  unsigned short* lA = &As[tid * 8];
  unsigned short* lB = &Bs[tid * 8];

  f32x16 acc[2][2] = {};
  const int nk = K >> 6;
  for (int kt = 0; kt < nk; ++kt) {
    __syncthreads();
#pragma unroll
    for (int s = 0; s < 4; ++s) {
      gload16(gA + (size_t)(s * 32) * K, lA + s * 2048);
      gload16(gB + (size_t)(s * 32) * K, lB + s * 2048);
    }
    gA += 64; gB += 64;
    __syncthreads();
#pragma unroll
    for (int ks = 0; ks < 4; ++ks) {
      const int ca = ((ks * 2 + hi) ^ rsw) * 8;   // swizzled chunk offset (shorts)
      bf16x8 a0 = *(const bf16x8*)(&As[(wr * 64 +      r31) * 64 + ca]);
      bf16x8 a1 = *(const bf16x8*)(&As[(wr * 64 + 32 + r31) * 64 + ca]);
      bf16x8 b0 = *(const bf16x8*)(&Bs[(wc * 64 +      r31) * 64 + ca]);
      bf16x8 b1 = *(const bf16x8*)(&Bs[(wc * 64 + 32 + r31) * 64 + ca]);
      acc[0][0] = __builtin_amdgcn_mfma_f32_32x32x16_bf16(a0, b0, acc[0][0], 0, 0, 0);
      acc[0][1] = __builtin_amdgcn_mfma_f32_32x32x16_bf16(a0, b1, acc[0][1], 0, 0, 0);
      acc[1][0] = __builtin_amdgcn_mfma_f32_32x32x16_bf16(a1, b0, acc[1][0], 0, 0, 0);
      acc[1][1] = __builtin_amdgcn_mfma_f32_32x32x16_bf16(a1, b1, acc[1][1], 0, 0, 0);
    }
  }

  const int row0 = bm * 128 + wr * 64;
  const int col0 = bn * 128 + wc * 64;
#pragma unroll
  for (int mt = 0; mt < 2; ++mt) {
#pragma unroll
    for (int nt = 0; nt < 2; ++nt) {
#pragma unroll
      for (int rg = 0; rg < 16; ++rg) {
        const int rl = (rg & 3) + 8 * (rg >> 2) + 4 * hi;
        const int row = row0 + mt * 32 + rl;
        const int col = col0 + nt * 32 + r31;
        const size_t idx = (size_t)row * N + col;
        const float v = acc[mt][nt][rg];
        if constexpr (EPI == 0) {
          ((unsigned short*)Cout)[idx] = f2bf(v);
        } else if constexpr (EPI == 1) {
          const float u = 0.7978845608028654f * (v + 0.044715f * v * v * v);
          const float gel = 0.5f * v * (1.0f + tanhf(u));
          ((unsigned short*)Cout)[idx] = f2bf(gel);
        } else {
          ((float*)Cout)[idx] = v + resid[idx];
        }
      }
    }
  }
}

// ---------------- 128x256 GEMM, 32x32x16 MFMA, BK=64, per-wave 64x128 ----------------
template<int EPI>
__global__ __launch_bounds__(256, 2)
void gemmW(const unsigned short* __restrict__ A,
           const unsigned short* __restrict__ Bt,
           void* __restrict__ Cout,
           const float* __restrict__ resid,
           int M, int N, int K) {
  __shared__ __align__(16) unsigned short As[128 * 64];   // 16 KB
  __shared__ __align__(16) unsigned short Bs[256 * 64];   // 32 KB
  const int gm = M >> 7;
  const int gn = N >> 8;
  const int nwg = gm * gn;
  const int cpx = nwg >> 3;
  const int bid = blockIdx.x;
  const int swz = (bid & 7) * cpx + (bid >> 3);
  const int cg = swz / (gm << 3);
  const int rr = swz - cg * (gm << 3);
  const int bm = rr >> 3;
  const int bn = (cg << 3) + (rr & 7);
  const int tid = threadIdx.x;
  const int wid = tid >> 6, lane = tid & 63;
  const int wr = wid >> 1, wc = wid & 1;
  const int r31 = lane & 31, hi = lane >> 5;
  const int rsw = r31 & 7;

  const int trow = tid >> 3;                      // 0..31
  const int tc = (tid & 7) ^ (trow & 7);          // chunk 0..7
  const unsigned short* gA = A  + (size_t)(bm * 128 + trow) * K + tc * 8;
  const unsigned short* gB = Bt + (size_t)(bn * 256 + trow) * K + tc * 8;
  unsigned short* lA = &As[tid * 8];
  unsigned short* lB = &Bs[tid * 8];

  f32x16 acc[2][4] = {};
  const int nk = K >> 6;
  for (int kt = 0; kt < nk; ++kt) {
    __syncthreads();
#pragma unroll
    for (int s = 0; s < 4; ++s)
      gload16(gA + (size_t)(s * 32) * K, lA + s * 2048);
#pragma unroll
    for (int s = 0; s < 8; ++s)
      gload16(gB + (size_t)(s * 32) * K, lB + s * 2048);
    gA += 64; gB += 64;
    __syncthreads();
#pragma unroll
    for (int ks = 0; ks < 4; ++ks) {
      const int ca = ((ks * 2 + hi) ^ rsw) * 8;   // swizzled chunk offset (shorts)
      bf16x8 a0 = *(const bf16x8*)(&As[(wr * 64 +      r31) * 64 + ca]);
      bf16x8 a1 = *(const bf16x8*)(&As[(wr * 64 + 32 + r31) * 64 + ca]);
      bf16x8 bq[4];
#pragma unroll
      for (int nt = 0; nt < 4; ++nt)
        bq[nt] = *(const bf16x8*)(&Bs[(wc * 128 + nt * 32 + r31) * 64 + ca]);
#pragma unroll
      for (int nt = 0; nt < 4; ++nt) {
        acc[0][nt] = __builtin_amdgcn_mfma_f32_32x32x16_bf16(a0, bq[nt], acc[0][nt], 0, 0, 0);
        acc[1][nt] = __builtin_amdgcn_mfma_f32_32x32x16_bf16(a1, bq[nt], acc[1][nt], 0, 0, 0);
      }
    }
  }

  const int row0 = bm * 128 + wr * 64;
  const int col0 = bn * 256 + wc * 128;
#pragma unroll
  for (int mt = 0; mt < 2; ++mt) {
#pragma unroll
    for (int nt = 0; nt < 4; ++nt) {
#pragma unroll
      for (int rg = 0; rg < 16; ++rg) {
        const int rl = (rg & 3) + 8 * (rg >> 2) + 4 * hi;
        const int row = row0 + mt * 32 + rl;
        const int col = col0 + nt * 32 + r31;
        const size_t idx = (size_t)row * N + col;
        const float v = acc[mt][nt][rg];
        if constexpr (EPI == 0) {
          ((unsigned short*)Cout)[idx] = f2bf(v);
        } else if constexpr (EPI == 1) {
          const float u = 0.7978845608028654f * (v + 0.044715f * v * v * v);
          const float gel = 0.5f * v * (1.0f + tanhf(u));
          ((unsigned short*)Cout)[idx] = f2bf(gel);
        } else {
          ((float*)Cout)[idx] = v + resid[idx];
        }
      }
    }
  }
}

// ---------------- extract V^T: qkv (T,6144) -> vT (B,H,D,S) bf16 ----------------
__global__ void extract_vT(const unsigned short* __restrict__ qkv, unsigned short* __restrict__ vT) {
  __shared__ unsigned short tile[32][34];
  const int bh = blockIdx.z;               // b*H + h
  const int b = bh >> 4, h = bh & 15;
  const int s0 = blockIdx.y * 32, d0 = blockIdx.x * 32;
  const int tx = threadIdx.x, ty = threadIdx.y;
#pragma unroll
  for (int j = 0; j < 4; ++j) {
    int s = s0 + ty + j * 8;
    tile[ty + j * 8][tx] = qkv[(size_t)(b * S_ + s) * 6144 + 4096 + h * 128 + d0 + tx];
  }
  __syncthreads();
#pragma unroll
  for (int j = 0; j < 4; ++j) {
    int d = d0 + ty + j * 8;
    vT[((size_t)bh * 128 + d) * 2048 + s0 + tx] = tile[tx][ty + j * 8];
  }
}

// ---------------- causal flash attention, KVBLK=64, balanced pairing ----------------
// R17: softmax denominator via ones-MFMA. l = sum_k P is a matmul against a
// ones B-fragment: accl = mfma(pf, ones, accl) using the P-fragment already
// loaded for PV. D-layout gives lane accl[r] for q-row g*4+r. Deletes the
// 16-shuffle sum-reduction per tile (half the softmax cross-lane work);
// rescale branch scales accl by corr. Denominator now sums bf16-rounded P -
// consistent with the bf16 PV numerator.
__global__ __launch_bounds__(256, 2)
void attn_kernel(const unsigned short* __restrict__ qkv,
                 const unsigned short* __restrict__ vT,
                 unsigned short* __restrict__ outp) {
  __shared__ __align__(16) unsigned short Ks[64 * 128];    // 16 KB, swizzled
  __shared__ __align__(16) unsigned short Vts[128 * 64];   // 16 KB, swizzled
  __shared__ __align__(16) unsigned short Ps[4 * 16 * 40]; // 5 KB, per-wave P tile
  const int bx = blockIdx.x;               // 0..15
  const int bh = blockIdx.y;
  const int b = bh >> 4, h = bh & 15;
  const int tid = threadIdx.x, wid = tid >> 6, lane = tid & 63;
  const int fr = lane & 15, g = lane >> 4;

  const unsigned short* kbase = qkv + (size_t)(b * S_) * 6144 + 2048 + h * 128;
  const unsigned short* vbase = vT + (size_t)bh * 128 * 2048;
  unsigned short* Pw = &Ps[wid * 640];
  const float scale = 0.08838834764831845f;

  bf16x8 onesf;
#pragma unroll
  for (int e = 0; e < 8; ++e) onesf[e] = (short)0x3F80;   // bf16 1.0

  us8 kreg[4], vreg[4];
#pragma unroll
  for (int j = 0; j < 4; ++j) {
    const int cc = tid + 256 * j;
    kreg[j] = *(const us8*)(kbase + (size_t)(cc >> 4) * 6144 + (cc & 15) * 8);
    vreg[j] = *(const us8*)(vbase + (size_t)(cc >> 3) * 2048 + (cc & 7) * 8);
  }

  for (int hf = 0; hf < 2; ++hf) {
    const int qt = hf ? (31 - bx) : bx;

    const unsigned short* qptr = qkv + (size_t)(b * S_ + qt * 64 + wid * 16 + fr) * 6144 + h * 128;
    bf16x8 qf[4];
#pragma unroll
    for (int dc = 0; dc < 4; ++dc) qf[dc] = *(const bf16x8*)(qptr + dc * 32 + g * 8);

    float m0[4];
#pragma unroll
    for (int r = 0; r < 4; ++r) m0[r] = -1e30f;
    f32x4 acc[8] = {};
    f32x4 accl = {};

    for (int kt = 0; kt <= qt; ++kt) {
      __syncthreads();
#pragma unroll
      for (int j = 0; j < 4; ++j) {
        const int cc = tid + 256 * j;
        const int krow = cc >> 4, kcp = cc & 15;
        *(us8*)(&Ks[krow * 128 + ((kcp * 8) ^ ((krow & 7) << 3))]) = kreg[j];
        const int drow = cc >> 3, vcp = cc & 7;
        *(us8*)(&Vts[drow * 64 + ((vcp * 8) ^ ((drow & 7) << 3))]) = vreg[j];
      }
      const int nk = (kt < qt) ? (kt + 1) : (hf == 0 ? 0 : -1);
      if (nk >= 0) {
#pragma unroll
        for (int j = 0; j < 4; ++j) {
          const int cc = tid + 256 * j;
          kreg[j] = *(const us8*)(kbase + (size_t)(nk * 64 + (cc >> 4)) * 6144 + (cc & 15) * 8);
          vreg[j] = *(const us8*)(vbase + (size_t)(cc >> 3) * 2048 + nk * 64 + (cc & 7) * 8);
        }
      }
      __syncthreads();

      f32x4 sc[4] = {};
      __builtin_amdgcn_s_setprio(1);
#pragma unroll
      for (int dc = 0; dc < 4; ++dc) {
#pragma unroll
        for (int sub = 0; sub < 4; ++sub) {
          const int row = sub * 16 + fr;
          bf16x8 kf = *(const bf16x8*)(&Ks[row * 128 + ((dc * 32 + g * 8) ^ ((row & 7) << 3))]);
          sc[sub] = __builtin_amdgcn_mfma_f32_16x16x32_bf16(qf[dc], kf, sc[sub], 0, 0, 0);
        }
      }
      __builtin_amdgcn_s_setprio(0);

      float p[4][4];
      const bool diag = (kt == qt);
#pragma unroll
      for (int sub = 0; sub < 4; ++sub) {
#pragma unroll
        for (int r = 0; r < 4; ++r) {
          float v = sc[sub][r] * scale;
          if (diag && (sub * 16 + fr > wid * 16 + g * 4 + r)) v = -1e30f;
          p[sub][r] = v;
        }
      }

      // row maxes for this tile
      float mx4[4];
      int small = 1;
#pragma unroll
      for (int r = 0; r < 4; ++r) {
        float mx = fmaxf(fmaxf(p[0][r], p[1][r]), fmaxf(p[2][r], p[3][r]));
#pragma unroll
        for (int off = 1; off < 16; off <<= 1) mx = fmaxf(mx, __shfl_xor(mx, off));
        mx4[r] = mx;
        small &= (mx <= m0[r] + 8.0f) ? 1 : 0;
      }
      if (__all(small)) {
        // defer-max: keep old m0, no rescale (P bounded by e^8)
#pragma unroll
        for (int r = 0; r < 4; ++r)
#pragma unroll
          for (int sub = 0; sub < 4; ++sub) p[sub][r] = __expf(p[sub][r] - m0[r]);
      } else {
#pragma unroll
        for (int r = 0; r < 4; ++r) {
          const float mn = fmaxf(m0[r], mx4[r]);
          const float corr = __expf(m0[r] - mn);
          m0[r] = mn;
#pragma unroll
          for (int sub = 0; sub < 4; ++sub) p[sub][r] = __expf(p[sub][r] - mn);
          accl[r] *= corr;
#pragma unroll
          for (int dt = 0; dt < 8; ++dt) acc[dt][r] *= corr;
        }
      }

#pragma unroll
      for (int half = 0; half < 2; ++half) {
#pragma unroll
        for (int s2 = 0; s2 < 2; ++s2)
#pragma unroll
          for (int r = 0; r < 4; ++r)
            Pw[(g * 4 + r) * 40 + s2 * 16 + fr] = f2bf(p[half * 2 + s2][r]);
        bf16x8 pf = *(const bf16x8*)(&Pw[fr * 40 + g * 8]);
        __builtin_amdgcn_s_setprio(1);
        accl = __builtin_amdgcn_mfma_f32_16x16x32_bf16(pf, onesf, accl, 0, 0, 0);
#pragma unroll
        for (int dt = 0; dt < 8; ++dt) {
          const int row = dt * 16 + fr;
          bf16x8 vf = *(const bf16x8*)(&Vts[row * 64 + ((half * 32 + g * 8) ^ ((row & 7) << 3))]);
          acc[dt] = __builtin_amdgcn_mfma_f32_16x16x32_bf16(pf, vf, acc[dt], 0, 0, 0);
        }
        __builtin_amdgcn_s_setprio(0);
      }
    }

    float inv[4];
#pragma unroll
    for (int r = 0; r < 4; ++r) inv[r] = 1.0f / accl[r];
#pragma unroll
    for (int dt = 0; dt < 8; ++dt)
#pragma unroll
      for (int r = 0; r < 4; ++r) {
        const size_t row = (size_t)(b * S_ + qt * 64 + wid * 16 + g * 4 + r);
        outp[row * E_ + h * 128 + dt * 16 + fr] = f2bf(acc[dt][r] * inv[r]);
      }
  }
}

// ---------------- launcher ----------------
extern "C" void kernel_launch(void* const* d_in, const int* in_sizes, int n_in,
                              void* d_out, int out_size, void* d_ws, size_t ws_size,
                              hipStream_t stream) {
  (void)in_sizes; (void)n_in; (void)out_size; (void)ws_size;
  const float* x    = (const float*)d_in[0];
  const float* ln1w = (const float*)d_in[1];
  const float* ln1b = (const float*)d_in[2];
  const float* Wqkv = (const float*)d_in[3];
  const float* Wo   = (const float*)d_in[4];
  const float* ln2w = (const float*)d_in[5];
  const float* ln2b = (const float*)d_in[6];
  const float* W1   = (const float*)d_in[7];
  const float* W2   = (const float*)d_in[8];
  float* out = (float*)d_out;
  char* ws = (char*)d_ws;

  // workspace layout (bytes)
  unsigned short* WqkvT = (unsigned short*)(ws + 0);            // 25,165,824
  unsigned short* WoT   = (unsigned short*)(ws + 25165824);     //  8,388,608
  unsigned short* W1T   = (unsigned short*)(ws + 33554432);     // 33,554,432
  unsigned short* W2T   = (unsigned short*)(ws + 67108864);     // 33,554,432
  unsigned short* qkvb  = (unsigned short*)(ws + 100663296);    // 50,331,648
  unsigned short* vTb   = (unsigned short*)(ws + 150994944);    // 16,777,216
  unsigned short* gbuf  = (unsigned short*)(ws + 100663296);    // 67,108,864 (reuses qkv+vT)
  unsigned short* hbuf  = (unsigned short*)(ws + 167772160);    // 16,777,216 (h / attnout / h2)
  float*          x1    = (float*)         (ws + 184549376);    // 33,554,432

  const dim3 tb(32, 8);
  hipLaunchKernelGGL(transpose_w, dim3(6144 / 32, 2048 / 32), tb, 0, stream, Wqkv, WqkvT, 2048, 6144);
  hipLaunchKernelGGL(transpose_w, dim3(2048 / 32, 2048 / 32), tb, 0, stream, Wo,   WoT,   2048, 2048);
  hipLaunchKernelGGL(transpose_w, dim3(8192 / 32, 2048 / 32), tb, 0, stream, W1,   W1T,   2048, 8192);
  hipLaunchKernelGGL(transpose_w, dim3(2048 / 32, 8192 / 32), tb, 0, stream, W2,   W2T,   8192, 2048);

  hipLaunchKernelGGL(ln_kernel, dim3(T_), dim3(256), 0, stream, x, ln1w, ln1b, hbuf);
  hipLaunchKernelGGL((gemmW<0>), dim3(32 * 24), dim3(256), 0, stream,
                     hbuf, WqkvT, (void*)qkvb, (const float*)nullptr, T_, 6144, 2048);
  hipLaunchKernelGGL(extract_vT, dim3(4, 64, 32), tb, 0, stream, qkvb, vTb);
  hipLaunchKernelGGL(attn_kernel, dim3(S_ / 128, B_ * H_), dim3(256), 0, stream, qkvb, vTb, hbuf);
  hipLaunchKernelGGL((gemm32<2>), dim3(32 * 16), dim3(256), 0, stream,
                     hbuf, WoT, (void*)x1, x, T_, 2048, 2048);
  hipLaunchKernelGGL(ln_kernel, dim3(T_), dim3(256), 0, stream, x1, ln2w, ln2b, hbuf);
  hipLaunchKernelGGL((gemmW<1>), dim3(32 * 32), dim3(256), 0, stream,
                     hbuf, W1T, (void*)gbuf, (const float*)nullptr, T_, 8192, 2048);
  hipLaunchKernelGGL((gemm32<2>), dim3(32 * 16), dim3(256), 0, stream,
                     gbuf, W2T, (void*)out, x1, T_, 2048, 8192);
}